// Round 1
// baseline (679.435 us; speedup 1.0000x reference)
//
#include <hip/hip_runtime.h>
#include <math.h>

#define NN 4096
#define EE 131072
#define NKMAX 32768

// ---- workspace layout (float offsets) ----
#define OFF_LN    ((size_t)0)
#define OFF_DIRN  (OFF_LN + EE)
#define OFF_R     (OFF_DIRN + (size_t)EE*3)
#define OFF_G     (OFF_R + (size_t)NN*128)
#define OFF_P1    (OFF_G + (size_t)NN*64)
#define OFF_HLS   (OFF_P1 + (size_t)NN*96)
#define OFF_HLV   (OFF_HLS + (size_t)NN*128)
#define OFF_MVAL  (OFF_HLV + (size_t)NN*96)
#define OFF_MASK  (OFF_MVAL + NN)
#define OFF_Q     (OFF_MASK + NN)
#define OFF_K     (OFF_Q + (size_t)NN*128)
#define OFF_A1    (OFF_K + (size_t)NN*128)
#define OFF_A2    (OFF_A1 + (size_t)NN*128)
#define OFF_R2    (OFF_A2 + (size_t)NN*128)
#define OFF_G2    (OFF_R2 + (size_t)NN*128)
#define OFF_P2    (OFF_G2 + (size_t)NN*64)
#define OFF_W3    (OFF_P2 + (size_t)NN*96)
#define OFF_LNV   (OFF_W3 + 128)
#define OFF_DIRV  (OFF_LNV + NKMAX)
#define OFF_SC    (OFF_DIRV + (size_t)NKMAX*3)
#define OFF_EEXP  (OFF_SC + NKMAX)
#define OFF_VEDGE (OFF_EEXP + NKMAX)
#define OFF_ZBEG  (OFF_VEDGE + (size_t)NKMAX*2)
#define OFF_S1S   (OFF_ZBEG)
#define OFF_S1V   (OFF_S1S + (size_t)NN*128)
#define OFF_S2S   (OFF_S1V + (size_t)NN*96)
#define OFF_S2V   (OFF_S2S + (size_t)NN*128)
#define OFF_DEN   (OFF_S2V + (size_t)NN*96)
#define OFF_MX    (OFF_DEN + NN)
#define OFF_ADJ   (OFF_MX + NN)            /* u64[NN*64] = NN*128 floats */
#define OFF_VCNT  (OFF_ADJ + (size_t)NN*128)
#define OFF_END   (OFF_VCNT + 64)

// ---- output layout (float offsets) ----
#define OUT_HFS 0
#define OUT_HFV 524288
#define OUT_POS 917504
#define OUT_AV  929792
#define OUT_M   17707008

// =======================================================================
// edge prep: ln, dirn, adjacency bitset
__global__ void hmp_edge_prep(const int* __restrict__ ei, const float* __restrict__ pos,
                              float* __restrict__ ln, float* __restrict__ dirn,
                              unsigned long long* __restrict__ adj) {
  int e = blockIdx.x * 256 + threadIdx.x;
  if (e >= EE) return;
  int s = ei[e], d = ei[EE + e];
  float vx = pos[s*3+0] - pos[d*3+0];
  float vy = pos[s*3+1] - pos[d*3+1];
  float vz = pos[s*3+2] - pos[d*3+2];
  float l = sqrtf(vx*vx + vy*vy + vz*vz);
  ln[e] = l;
  if (l > 1e-12f) {
    dirn[e*3+0] = vx / l; dirn[e*3+1] = vy / l; dirn[e*3+2] = vz / l;
  } else {
    dirn[e*3+0] = 0.f; dirn[e*3+1] = 0.f; dirn[e*3+2] = 0.f;
  }
  atomicOr(&adj[(size_t)s*64 + (d >> 6)], 1ULL << (d & 63));
}

// =======================================================================
// generic tiled f32 GEMM, M=4096, K=128, Nc in {64,128}, multi-job via blockIdx.z
struct GemmJobs {
  const float* A;
  const float* W[6];
  float* C[6];
  int Nc[6];
  int act[6];       // 0 none, 1 relu, 2 +res, 3 final_s blend
  const float* res;
  const float* mval;
  const float* maskf;
};

__global__ __launch_bounds__(256) void hmp_gemm_k128(GemmJobs P) {
  const int g = blockIdx.z;
  const int nc = P.Nc[g];
  if ((int)blockIdx.y * 64 >= nc) return;
  const float* __restrict__ W = P.W[g];
  float* __restrict__ C = P.C[g];
  const int act = P.act[g];
  __shared__ float As[32][68];
  __shared__ float Bs[32][64];
  const int tid = threadIdx.x;
  const int row0 = blockIdx.x * 64, col0 = blockIdx.y * 64;
  const int ty = tid >> 4, tx = tid & 15;
  float acc[4][4];
  #pragma unroll
  for (int i = 0; i < 4; ++i)
    #pragma unroll
    for (int j = 0; j < 4; ++j) acc[i][j] = 0.f;

  for (int kb = 0; kb < 4; ++kb) {
    #pragma unroll
    for (int q = 0; q < 2; ++q) {
      int f4 = tid + 256*q;
      int r = f4 >> 3, cg = f4 & 7;
      float4 av = *(const float4*)&P.A[(size_t)(row0+r)*128 + kb*32 + cg*4];
      As[cg*4+0][r] = av.x; As[cg*4+1][r] = av.y; As[cg*4+2][r] = av.z; As[cg*4+3][r] = av.w;
    }
    #pragma unroll
    for (int q = 0; q < 2; ++q) {
      int f4 = tid + 256*q;
      int kr = f4 >> 4, cg = f4 & 15;
      *(float4*)&Bs[kr][cg*4] = *(const float4*)&W[(size_t)(kb*32+kr)*nc + col0 + cg*4];
    }
    __syncthreads();
    #pragma unroll
    for (int kk = 0; kk < 32; ++kk) {
      float4 a = *(float4*)&As[kk][ty*4];
      float4 b = *(float4*)&Bs[kk][tx*4];
      acc[0][0] += a.x*b.x; acc[0][1] += a.x*b.y; acc[0][2] += a.x*b.z; acc[0][3] += a.x*b.w;
      acc[1][0] += a.y*b.x; acc[1][1] += a.y*b.y; acc[1][2] += a.y*b.z; acc[1][3] += a.y*b.w;
      acc[2][0] += a.z*b.x; acc[2][1] += a.z*b.y; acc[2][2] += a.z*b.z; acc[2][3] += a.z*b.w;
      acc[3][0] += a.w*b.x; acc[3][1] += a.w*b.y; acc[3][2] += a.w*b.z; acc[3][3] += a.w*b.w;
    }
    __syncthreads();
  }
  #pragma unroll
  for (int i = 0; i < 4; ++i) {
    int rr = row0 + ty*4 + i;
    float mv = 0.f, mk = 0.f;
    if (act == 3) { mv = P.mval[rr]; mk = P.maskf[rr]; }
    #pragma unroll
    for (int j = 0; j < 4; ++j) {
      int cc = col0 + tx*4 + j;
      float v = acc[i][j];
      if (act == 1) v = fmaxf(v, 0.f);
      else if (act == 2) v += P.res[(size_t)rr*128 + cc];
      else if (act == 3) {
        float hl = P.res[(size_t)rr*128 + cc];
        v = (1.f - mv)*hl + mv*mk*(hl + v);
      }
      C[(size_t)rr*nc + cc] = v;
    }
  }
}

// =======================================================================
// P1[n][v*3+c] = h_v[n][v][c] * G[n][v]   (g1 half)
__global__ void hmp_mul_p1(const float* __restrict__ hv, const float* __restrict__ G,
                           float* __restrict__ P1) {
  int i = blockIdx.x * 256 + threadIdx.x;
  if (i >= NN*96) return;
  int n = i / 96, q = i - n*96, v = q / 3;
  P1[i] = hv[i] * G[(size_t)n*64 + v];
}

// hl_v = h_v + S1v ; P2 = hl_v * G2[:, :V]
__global__ void hmp_hlv_p2(const float* __restrict__ hv, const float* __restrict__ S1v,
                           const float* __restrict__ G2, float* __restrict__ hlv,
                           float* __restrict__ P2) {
  int i = blockIdx.x * 256 + threadIdx.x;
  if (i >= NN*96) return;
  int n = i / 96, q = i - n*96, v = q / 3;
  float x = hv[i] + S1v[i];
  hlv[i] = x;
  P2[i] = x * G2[(size_t)n*64 + v];
}

// =======================================================================
// real-edge scalar messages: S[d][c] += ln[e]*R[s][c]   (optional mask gate)
__global__ void hmp_msg_s(const int* __restrict__ ei, const float* __restrict__ ln,
                          const float* __restrict__ R, float* __restrict__ S,
                          const float* __restrict__ maskf) {
  int idx = blockIdx.x * 256 + threadIdx.x;
  int e = idx >> 7, c = idx & 127;
  int s = ei[e], d = ei[EE + e];
  if (maskf) { if (maskf[s] == 0.f || maskf[d] == 0.f) return; }
  atomicAdd(&S[(size_t)d*128 + c], ln[e] * R[(size_t)s*128 + c]);
}

// real-edge vector messages: Sv[d][q] += P[s][q] + dirn[e][c]*G[s][32+v]
__global__ void hmp_msg_v(const int* __restrict__ ei, const float* __restrict__ dirn,
                          const float* __restrict__ P, const float* __restrict__ G,
                          float* __restrict__ Sv, const float* __restrict__ maskf) {
  int idx = blockIdx.x * 256 + threadIdx.x;
  int e = idx / 96, q = idx - e*96;
  int v = q / 3, c = q - v*3;
  int s = ei[e], d = ei[EE + e];
  if (maskf) { if (maskf[s] == 0.f || maskf[d] == 0.f) return; }
  float msg = P[(size_t)s*96 + q] + dirn[(size_t)e*3 + c] * G[(size_t)s*64 + 32 + v];
  atomicAdd(&Sv[(size_t)d*96 + q], msg);
}

// =======================================================================
// master-score MLP: m = sigmoid(relu(hl_s@Wm1+bm1)@Wm2+bm2); mask = m>0.5
__global__ __launch_bounds__(256) void hmp_master(const float* __restrict__ hls,
                                                  const float* __restrict__ Wm1,
                                                  const float* __restrict__ bm1,
                                                  const float* __restrict__ Wm2,
                                                  const float* __restrict__ bm2,
                                                  float* __restrict__ mval,
                                                  float* __restrict__ maskf,
                                                  float* __restrict__ out_m) {
  __shared__ float sW[128*64];
  __shared__ float sx[4][128];
  int tid = threadIdx.x;
  for (int i = tid; i < 8192; i += 256) sW[i] = Wm1[i];
  for (int i = tid; i < 512; i += 256) {
    int nn = i >> 7;
    sx[nn][i & 127] = hls[(size_t)(blockIdx.x*4 + nn)*128 + (i & 127)];
  }
  __syncthreads();
  int nl = tid >> 6, lane = tid & 63;
  int n = blockIdx.x * 4 + nl;
  float h = bm1[lane];
  for (int k = 0; k < 128; ++k) h += sx[nl][k] * sW[k*64 + lane];
  h = fmaxf(h, 0.f) * Wm2[lane];
  for (int off = 32; off; off >>= 1) h += __shfl_down(h, off, 64);
  if (lane == 0) {
    float logit = h + bm2[0];
    float mv = 1.f / (1.f + expf(-logit));
    mval[n] = mv;
    maskf[n] = (mv > 0.5f) ? 1.f : 0.f;
    out_m[n] = mv;
  }
}

// w3[s] = sum_k Wa1[256+k][s]
__global__ void hmp_colsum_w3(const float* __restrict__ Wa1, float* __restrict__ w3) {
  int s = threadIdx.x;
  float acc = 0.f;
  for (int k = 0; k < 128; ++k) acc += Wa1[(size_t)(256 + k)*128 + s];
  w3[s] = acc;
}

// =======================================================================
// fused attention + exact stable top-8 (value desc, index asc) + edge emit
__global__ __launch_bounds__(256) void hmp_attn_topk(const float* __restrict__ Q,
                                                     const float* __restrict__ Kk,
                                                     const float* __restrict__ maskf,
                                                     const unsigned long long* __restrict__ adj,
                                                     float* __restrict__ Avirt,
                                                     int2* __restrict__ vedges,
                                                     int* __restrict__ vcnt) {
  __shared__ float sQ[8][128];
  __shared__ float sK[64][132];
  __shared__ unsigned long long sAdj[8][64];
  __shared__ float sMk[64];
  const int tid = threadIdx.x;
  const int row0 = blockIdx.x * 8;
  const int r = tid >> 5, l = tid & 31;
  {
    int rr = tid >> 5, c = tid & 31;
    *(float4*)&sQ[rr][c*4] = *(const float4*)&Q[(size_t)(row0+rr)*128 + c*4];
  }
  for (int i = tid; i < 512; i += 256)
    sAdj[i >> 6][i & 63] = adj[(size_t)(row0 + (i >> 6))*64 + (i & 63)];
  __syncthreads();
  const int grow = row0 + r;
  const bool rowAct = maskf[grow] > 0.5f;

  float tv[8]; int tc[8];
  #pragma unroll
  for (int k = 0; k < 8; ++k) { tv[k] = -1.f; tc[k] = 0x7fffffff; }

  for (int t = 0; t < 64; ++t) {
    const float4* src = (const float4*)(Kk + (size_t)t*64*128);
    #pragma unroll
    for (int q = 0; q < 8; ++q) {
      int f4 = q*256 + tid;
      int rr = f4 >> 5, c = f4 & 31;
      *(float4*)&sK[rr][c*4] = src[f4];
    }
    if (tid < 64) sMk[tid] = maskf[t*64 + tid];
    __syncthreads();
    if (rowAct) {
      #pragma unroll
      for (int half = 0; half < 2; ++half) {
        int jj = l + half*32;
        int j = t*64 + jj;
        bool ok = (sMk[jj] > 0.5f) && (j != grow) &&
                  !((sAdj[r][j >> 6] >> (j & 63)) & 1ULL);
        if (ok) {
          float ax = 0.f, ay = 0.f, az = 0.f, aw = 0.f;
          #pragma unroll
          for (int kk = 0; kk < 32; ++kk) {
            float4 a = *(float4*)&sQ[r][kk*4];
            float4 b = *(float4*)&sK[jj][kk*4];
            ax += a.x*b.x; ay += a.y*b.y; az += a.z*b.z; aw += a.w*b.w;
          }
          float dot = (ax + ay) + (az + aw);
          float z = dot / 11.3137085f;               // / sqrt(128)
          float attn = 1.f / (1.f + expf(-z));
          if (attn > tv[7]) {                        // stable insert (static idx only)
            #pragma unroll
            for (int k = 7; k >= 1; --k) {
              bool gtk = attn > tv[k];
              bool gtm = attn > tv[k-1];
              float nv = gtk ? (gtm ? tv[k-1] : attn) : tv[k];
              int   ni = gtk ? (gtm ? tc[k-1] : j)    : tc[k];
              tv[k] = nv; tc[k] = ni;
            }
            bool gt0 = attn > tv[0];
            if (gt0) { /* old tv[0] already shifted to slot 1 */ }
            tv[0] = gt0 ? attn : tv[0];
            tc[0] = gt0 ? j    : tc[0];
          }
        }
      }
    }
    __syncthreads();
  }

  // butterfly merge of 32 per-lane sorted-8 lists (bitonic, static indices)
  #pragma unroll
  for (int m = 1; m <= 16; m <<= 1) {
    float av[16]; int ac[16];
    #pragma unroll
    for (int k = 0; k < 8; ++k) { av[k] = tv[k]; ac[k] = tc[k]; }
    #pragma unroll
    for (int k = 0; k < 8; ++k) {
      av[8+k] = __shfl_xor(tv[7-k], m, 64);   // reversed partner list -> bitonic
      ac[8+k] = __shfl_xor(tc[7-k], m, 64);
    }
    #pragma unroll
    for (int d = 8; d >= 1; d >>= 1) {
      #pragma unroll
      for (int i = 0; i < 16; ++i) {
        if ((i & d) == 0) {
          const int jx = i + d;
          if (jx < 16) {
            bool sw = (av[i] < av[jx]) || (av[i] == av[jx] && ac[i] > ac[jx]);
            float t1 = sw ? av[jx] : av[i]; float t2 = sw ? av[i] : av[jx];
            int   u1 = sw ? ac[jx] : ac[i]; int   u2 = sw ? ac[i] : ac[jx];
            av[i] = t1; av[jx] = t2; ac[i] = u1; ac[jx] = u2;
          }
        }
      }
    }
    #pragma unroll
    for (int k = 0; k < 8; ++k) { tv[k] = av[k]; tc[k] = ac[k]; }
  }

  if (l == 0 && rowAct) {
    #pragma unroll
    for (int k = 0; k < 8; ++k) {
      if (tv[k] > 0.55f) {
        int col = tc[k];
        Avirt[(size_t)grow*NN + col] = 1.f;
        int slot = atomicAdd(vcnt, 1);
        vedges[slot] = make_int2(grow, col);
      }
    }
  }
}

// =======================================================================
// virtual-edge features + attention-MLP score + segment max (encoded atomicMax)
__global__ __launch_bounds__(256) void hmp_vedge_sc(const int2* __restrict__ ve,
                                                    const int* __restrict__ vcnt,
                                                    const float* __restrict__ pos,
                                                    const float* __restrict__ A1,
                                                    const float* __restrict__ A2,
                                                    const float* __restrict__ w3,
                                                    const float* __restrict__ ba1,
                                                    const float* __restrict__ Wa2,
                                                    const float* __restrict__ ba2,
                                                    float* __restrict__ lnv,
                                                    float* __restrict__ dirv,
                                                    float* __restrict__ sc,
                                                    unsigned int* __restrict__ mxenc) {
  int e = blockIdx.x * 4 + (threadIdx.x >> 6);
  int lane = threadIdx.x & 63;
  if (e >= *vcnt) return;
  int2 ed = ve[e];
  int i = ed.x, j = ed.y;
  float vx = pos[i*3+0] - pos[j*3+0];
  float vy = pos[i*3+1] - pos[j*3+1];
  float vz = pos[i*3+2] - pos[j*3+2];
  float lval = sqrtf(vx*vx + vy*vy + vz*vz);
  float acc = 0.f;
  #pragma unroll
  for (int half = 0; half < 2; ++half) {
    int c = lane + half*64;
    float tq = A1[(size_t)i*128 + c] + A2[(size_t)j*128 + c] + lval*w3[c] + ba1[c];
    acc += fmaxf(tq, 0.f) * Wa2[c];
  }
  for (int off = 32; off; off >>= 1) acc += __shfl_down(acc, off, 64);
  if (lane == 0) {
    lnv[e] = lval;
    if (lval > 1e-12f) {
      dirv[e*3+0] = vx / lval; dirv[e*3+1] = vy / lval; dirv[e*3+2] = vz / lval;
    } else {
      dirv[e*3+0] = 0.f; dirv[e*3+1] = 0.f; dirv[e*3+2] = 0.f;
    }
    float s = acc + ba2[0];
    sc[e] = s;
    unsigned int bits = __float_as_uint(s);
    unsigned int enc = (bits & 0x80000000u) ? ~bits : (bits | 0x80000000u);
    atomicMax(&mxenc[j], enc);
  }
}

// exp(sc - mx) and denominator
__global__ void hmp_vexp(const int2* __restrict__ ve, const int* __restrict__ vcnt,
                         const float* __restrict__ sc, const unsigned int* __restrict__ mxenc,
                         float* __restrict__ eexp, float* __restrict__ den) {
  int e = blockIdx.x * 256 + threadIdx.x;
  if (e >= *vcnt) return;
  int j = ve[e].y;
  unsigned int enc = mxenc[j];
  unsigned int bits = (enc & 0x80000000u) ? (enc & 0x7fffffffu) : ~enc;
  float mx = __uint_as_float(bits);
  float ex = expf(sc[e] - mx);
  eexp[e] = ex;
  atomicAdd(&den[j], ex);
}

// virtual-edge scalar messages
__global__ void hmp_msgv_s(const int2* __restrict__ ve, const int* __restrict__ vcnt,
                           const float* __restrict__ eexp, const float* __restrict__ den,
                           const float* __restrict__ lnv, const float* __restrict__ R2,
                           float* __restrict__ S2s) {
  int idx = blockIdx.x * 256 + threadIdx.x;
  int e = idx >> 7, c = idx & 127;
  if (e >= *vcnt) return;
  int2 ed = ve[e];
  float decay = eexp[e] / fmaxf(den[ed.y], 1e-9f);
  atomicAdd(&S2s[(size_t)ed.y*128 + c], lnv[e] * decay * R2[(size_t)ed.x*128 + c]);
}

// virtual-edge vector messages
__global__ void hmp_msgv_v(const int2* __restrict__ ve, const int* __restrict__ vcnt,
                           const float* __restrict__ eexp, const float* __restrict__ den,
                           const float* __restrict__ dirv, const float* __restrict__ P2,
                           const float* __restrict__ G2, float* __restrict__ S2v) {
  int idx = blockIdx.x * 256 + threadIdx.x;
  int e = idx / 96, q = idx - e*96;
  if (e >= *vcnt) return;
  int v = q / 3, c = q - v*3;
  int2 ed = ve[e];
  float decay = eexp[e] / fmaxf(den[ed.y], 1e-9f);
  float msg = P2[(size_t)ed.x*96 + q] + dirv[(size_t)e*3 + c] * decay * G2[(size_t)ed.x*64 + 32 + v];
  atomicAdd(&S2v[(size_t)ed.y*96 + q], msg);
}

// final vector blend
__global__ void hmp_final_v(const float* __restrict__ hlv, const float* __restrict__ S2v,
                            const float* __restrict__ mval, const float* __restrict__ maskf,
                            float* __restrict__ out) {
  int idx = blockIdx.x * 256 + threadIdx.x;
  if (idx >= NN*96) return;
  int n = idx / 96;
  float mv = mval[n], mk = maskf[n];
  float x = hlv[idx];
  out[idx] = (1.f - mv)*x + mv*mk*(x + S2v[idx]);
}

// =======================================================================
extern "C" void kernel_launch(void* const* d_in, const int* in_sizes, int n_in,
                              void* d_out, int out_size, void* d_ws, size_t ws_size,
                              hipStream_t stream) {
  const float* h_s = (const float*)d_in[0];
  const float* h_v = (const float*)d_in[1];
  const float* pos = (const float*)d_in[2];
  const int*   ei  = (const int*)d_in[3];
  const float* W1  = (const float*)d_in[5];
  const float* Wg  = (const float*)d_in[6];
  const float* W2  = (const float*)d_in[7];
  const float* Wm1 = (const float*)d_in[8];
  const float* bm1 = (const float*)d_in[9];
  const float* Wm2 = (const float*)d_in[10];
  const float* bm2 = (const float*)d_in[11];
  const float* Wq  = (const float*)d_in[12];
  const float* Wk  = (const float*)d_in[13];
  const float* Wa1 = (const float*)d_in[14];
  const float* ba1 = (const float*)d_in[15];
  const float* Wa2 = (const float*)d_in[16];
  const float* ba2 = (const float*)d_in[17];

  if (ws_size < OFF_END * sizeof(float)) return;  // insufficient scratch

  float* ws  = (float*)d_ws;
  float* out = (float*)d_out;

  float* ln   = ws + OFF_LN;
  float* dirn = ws + OFF_DIRN;
  float* R    = ws + OFF_R;
  float* G    = ws + OFF_G;
  float* P1   = ws + OFF_P1;
  float* hls  = ws + OFF_HLS;
  float* hlv  = ws + OFF_HLV;
  float* mval = ws + OFF_MVAL;
  float* mskf = ws + OFF_MASK;
  float* Qb   = ws + OFF_Q;
  float* Kb   = ws + OFF_K;
  float* A1   = ws + OFF_A1;
  float* A2   = ws + OFF_A2;
  float* R2   = ws + OFF_R2;
  float* G2   = ws + OFF_G2;
  float* P2   = ws + OFF_P2;
  float* w3   = ws + OFF_W3;
  float* lnv  = ws + OFF_LNV;
  float* dirv = ws + OFF_DIRV;
  float* sc   = ws + OFF_SC;
  float* eexp = ws + OFF_EEXP;
  int2*  vedg = (int2*)(ws + OFF_VEDGE);
  float* S1s  = ws + OFF_S1S;
  float* S1v  = ws + OFF_S1V;
  float* S2s  = ws + OFF_S2S;
  float* S2v  = ws + OFF_S2V;
  float* den  = ws + OFF_DEN;
  unsigned int* mxenc = (unsigned int*)(ws + OFF_MX);
  unsigned long long* adj = (unsigned long long*)(ws + OFF_ADJ);
  int*   vcnt = (int*)(ws + OFF_VCNT);

  // zero scatter buffers + counters + adjacency + A_virtual; copy pos through
  hipMemsetAsync(ws + OFF_ZBEG, 0, (OFF_END - OFF_ZBEG) * sizeof(float), stream);
  hipMemsetAsync(out + OUT_AV, 0, (size_t)NN * NN * sizeof(float), stream);
  hipMemcpyAsync(out + OUT_POS, pos, (size_t)NN * 3 * sizeof(float),
                 hipMemcpyDeviceToDevice, stream);

  hmp_edge_prep<<<EE/256, 256, 0, stream>>>(ei, pos, ln, dirn, adj);

  { // R = relu(h_s@W1), G = h_s@Wg
    GemmJobs J = {};
    J.A = h_s;
    J.W[0] = W1; J.C[0] = R; J.Nc[0] = 128; J.act[0] = 1;
    J.W[1] = Wg; J.C[1] = G; J.Nc[1] = 64;  J.act[1] = 0;
    hmp_gemm_k128<<<dim3(64,2,2), 256, 0, stream>>>(J);
  }
  hmp_mul_p1<<<NN*96/256, 256, 0, stream>>>(h_v, G, P1);
  hmp_msg_s<<<EE*128/256, 256, 0, stream>>>(ei, ln, R, S1s, nullptr);
  hmp_msg_v<<<EE*96/256, 256, 0, stream>>>(ei, dirn, P1, G, S1v, nullptr);

  { // hl_s = S1s@W2 + h_s
    GemmJobs J = {};
    J.A = S1s; J.res = h_s;
    J.W[0] = W2; J.C[0] = hls; J.Nc[0] = 128; J.act[0] = 2;
    hmp_gemm_k128<<<dim3(64,2,1), 256, 0, stream>>>(J);
  }

  hmp_master<<<NN/4, 256, 0, stream>>>(hls, Wm1, bm1, Wm2, bm2, mval, mskf, out + OUT_M);

  { // Q, K, A1, A2, R2=relu(hl_s@W1), G2=hl_s@Wg
    GemmJobs J = {};
    J.A = hls;
    J.W[0] = Wq;          J.C[0] = Qb; J.Nc[0] = 128; J.act[0] = 0;
    J.W[1] = Wk;          J.C[1] = Kb; J.Nc[1] = 128; J.act[1] = 0;
    J.W[2] = Wa1;         J.C[2] = A1; J.Nc[2] = 128; J.act[2] = 0;
    J.W[3] = Wa1 + 16384; J.C[3] = A2; J.Nc[3] = 128; J.act[3] = 0;
    J.W[4] = W1;          J.C[4] = R2; J.Nc[4] = 128; J.act[4] = 1;
    J.W[5] = Wg;          J.C[5] = G2; J.Nc[5] = 64;  J.act[5] = 0;
    hmp_gemm_k128<<<dim3(64,2,6), 256, 0, stream>>>(J);
  }
  hmp_colsum_w3<<<1, 128, 0, stream>>>(Wa1, w3);
  hmp_hlv_p2<<<NN*96/256, 256, 0, stream>>>(h_v, S1v, G2, hlv, P2);

  hmp_attn_topk<<<NN/8, 256, 0, stream>>>(Qb, Kb, mskf, adj, out + OUT_AV, vedg, vcnt);

  hmp_vedge_sc<<<NKMAX/4, 256, 0, stream>>>(vedg, vcnt, pos, A1, A2, w3, ba1, Wa2, ba2,
                                            lnv, dirv, sc, mxenc);
  hmp_vexp<<<NKMAX/256, 256, 0, stream>>>(vedg, vcnt, sc, mxenc, eexp, den);

  hmp_msg_s<<<EE*128/256, 256, 0, stream>>>(ei, ln, R2, S2s, mskf);
  hmp_msg_v<<<EE*96/256, 256, 0, stream>>>(ei, dirn, P2, G2, S2v, mskf);
  hmp_msgv_s<<<NKMAX*128/256, 256, 0, stream>>>(vedg, vcnt, eexp, den, lnv, R2, S2s);
  hmp_msgv_v<<<NKMAX*96/256, 256, 0, stream>>>(vedg, vcnt, eexp, den, dirv, P2, G2, S2v);

  { // hf_s = (1-m)*hl_s + m*mask*(hl_s + S2s@W2)
    GemmJobs J = {};
    J.A = S2s; J.res = hls; J.mval = mval; J.maskf = mskf;
    J.W[0] = W2; J.C[0] = out + OUT_HFS; J.Nc[0] = 128; J.act[0] = 3;
    hmp_gemm_k128<<<dim3(64,2,1), 256, 0, stream>>>(J);
  }
  hmp_final_v<<<NN*96/256, 256, 0, stream>>>(hlv, S2v, mval, mskf, out + OUT_HFV);
}

// Round 4
// 543.354 us; speedup vs baseline: 1.2504x; 1.2504x over previous
//
#include <hip/hip_runtime.h>
#include <math.h>

#define NN 4096
#define EE 131072
#define NKMAX 32768

#define SCALE_FX 8388608.0      /* 2^23 fixed-point scale */
#define INV_FX   (1.0/8388608.0)

__device__ __forceinline__ void atomAddFx(long long* p, float v) {
  atomicAdd((unsigned long long*)p, (unsigned long long)llrint((double)v * SCALE_FX));
}
__device__ __forceinline__ float fxToF(long long v) {
  return (float)((double)v * INV_FX);
}

// ---- workspace layout (float offsets) ----
#define OFF_LN    ((size_t)0)
#define OFF_DIRN  (OFF_LN + EE)
#define OFF_R     (OFF_DIRN + (size_t)EE*3)
#define OFF_G     (OFF_R + (size_t)NN*128)
#define OFF_P1    (OFF_G + (size_t)NN*64)
#define OFF_HLS   (OFF_P1 + (size_t)NN*96)
#define OFF_HLV   (OFF_HLS + (size_t)NN*128)
#define OFF_MVAL  (OFF_HLV + (size_t)NN*96)
#define OFF_MASK  (OFF_MVAL + NN)
#define OFF_Q     (OFF_MASK + NN)
#define OFF_K     (OFF_Q + (size_t)NN*128)
#define OFF_A1    (OFF_K + (size_t)NN*128)
#define OFF_A2    (OFF_A1 + (size_t)NN*128)
#define OFF_R2    (OFF_A2 + (size_t)NN*128)
#define OFF_G2    (OFF_R2 + (size_t)NN*128)
#define OFF_P2    (OFF_G2 + (size_t)NN*64)
#define OFF_W3    (OFF_P2 + (size_t)NN*96)
#define OFF_LNV   (OFF_W3 + 128)
#define OFF_DIRV  (OFF_LNV + NKMAX)
#define OFF_SC    (OFF_DIRV + (size_t)NKMAX*3)
#define OFF_EEXP  (OFF_SC + NKMAX)
#define OFF_VEDGE (OFF_EEXP + NKMAX)
#define OFF_MIDX  (OFF_VEDGE + (size_t)NKMAX*2)
#define OFF_PT    (OFF_MIDX + NN)              /* int2[NN*16] = NN*32 floats */
#define OFF_MEDGE (OFF_PT + (size_t)NN*32)
#define OFF_SF    (OFF_MEDGE + EE)             /* float staging for S1s/S2s GEMM A */
#define OFF_ZBEG  (OFF_SF + (size_t)NN*128)
#define OFF_ACCS  (OFF_ZBEG)                   /* i64[NN*128] scalar msg accum (pass1 then pass2) */
#define OFF_ACCV  (OFF_ACCS + (size_t)NN*256)  /* i64[NN*96] vector msg accum */
#define OFF_DEN64 (OFF_ACCV + (size_t)NN*192)  /* i64[NN] softmax denom */
#define OFF_MX    (OFF_DEN64 + (size_t)NN*2)
#define OFF_ADJ   (OFF_MX + NN)                /* u64[NN*64] adjacency bitset */
#define OFF_CNT   (OFF_ADJ + (size_t)NN*128)   /* [0]=vcnt [1]=mecnt [2]=nm */
#define OFF_END   (OFF_CNT + 64)

// ---- output layout (float offsets) ----
#define OUT_HFS 0
#define OUT_HFV 524288
#define OUT_POS 917504
#define OUT_AV  929792
#define OUT_M   17707008

// exact stable insert into sorted-desc 8-list; requires ascending idx stream
// for correct tie handling (strict > keeps earliest = smallest idx).
#define INSERT8(TV, TC, VAL, IDX) do { \
  if ((VAL) > TV[7]) { \
    _Pragma("unroll") \
    for (int k_ = 7; k_ >= 1; --k_) { \
      bool gtk_ = (VAL) > TV[k_]; bool gtm_ = (VAL) > TV[k_-1]; \
      float nv_ = gtk_ ? (gtm_ ? TV[k_-1] : (VAL)) : TV[k_]; \
      int   ni_ = gtk_ ? (gtm_ ? TC[k_-1] : (IDX)) : TC[k_]; \
      TV[k_] = nv_; TC[k_] = ni_; } \
    bool gt0_ = (VAL) > TV[0]; \
    TV[0] = gt0_ ? (VAL) : TV[0]; TC[0] = gt0_ ? (IDX) : TC[0]; \
  } } while (0)

// butterfly merge of 32 per-lane sorted-8 lists within each 32-lane half
// (xor masks 1..16 never cross the 32 boundary); value desc, idx asc.
__device__ __forceinline__ void merge32(float (&tv)[8], int (&tc)[8]) {
  #pragma unroll
  for (int m = 1; m <= 16; m <<= 1) {
    float av[16]; int ac[16];
    #pragma unroll
    for (int k = 0; k < 8; ++k) { av[k] = tv[k]; ac[k] = tc[k]; }
    #pragma unroll
    for (int k = 0; k < 8; ++k) {
      av[8+k] = __shfl_xor(tv[7-k], m, 64);
      ac[8+k] = __shfl_xor(tc[7-k], m, 64);
    }
    #pragma unroll
    for (int d = 8; d >= 1; d >>= 1) {
      #pragma unroll
      for (int i = 0; i < 16; ++i) {
        if ((i & d) == 0) {
          const int jx = i + d;
          if (jx < 16) {
            bool sw = (av[i] < av[jx]) || (av[i] == av[jx] && ac[i] > ac[jx]);
            float t1 = sw ? av[jx] : av[i]; float t2 = sw ? av[i] : av[jx];
            int   u1 = sw ? ac[jx] : ac[i]; int   u2 = sw ? ac[i] : ac[jx];
            av[i] = t1; av[jx] = t2; ac[i] = u1; ac[jx] = u2;
          }
        }
      }
    }
    #pragma unroll
    for (int k = 0; k < 8; ++k) { tv[k] = av[k]; tc[k] = ac[k]; }
  }
}

// =======================================================================
__global__ void hmp_edge_prep(const int* __restrict__ ei, const float* __restrict__ pos,
                              float* __restrict__ ln, float* __restrict__ dirn,
                              unsigned long long* __restrict__ adj) {
  int e = blockIdx.x * 256 + threadIdx.x;
  if (e >= EE) return;
  int s = ei[e], d = ei[EE + e];
  float vx = pos[s*3+0] - pos[d*3+0];
  float vy = pos[s*3+1] - pos[d*3+1];
  float vz = pos[s*3+2] - pos[d*3+2];
  float l = sqrtf(vx*vx + vy*vy + vz*vz);
  ln[e] = l;
  if (l > 1e-12f) {
    dirn[e*3+0] = vx / l; dirn[e*3+1] = vy / l; dirn[e*3+2] = vz / l;
  } else {
    dirn[e*3+0] = 0.f; dirn[e*3+1] = 0.f; dirn[e*3+2] = 0.f;
  }
  atomicOr(&adj[(size_t)s*64 + (d >> 6)], 1ULL << (d & 63));
}

// =======================================================================
struct GemmJobs {
  const float* A;
  const float* W[6];
  float* C[6];
  int Nc[6];
  int act[6];       // 0 none, 1 relu, 2 +res, 3 final_s blend
  const float* res;
  const float* mval;
  const float* maskf;
};

__global__ __launch_bounds__(256) void hmp_gemm_k128(GemmJobs P) {
  const int g = blockIdx.z;
  const int nc = P.Nc[g];
  if ((int)blockIdx.y * 64 >= nc) return;
  const float* __restrict__ W = P.W[g];
  float* __restrict__ C = P.C[g];
  const int act = P.act[g];
  __shared__ float As[32][68];
  __shared__ float Bs[32][64];
  const int tid = threadIdx.x;
  const int row0 = blockIdx.x * 64, col0 = blockIdx.y * 64;
  const int ty = tid >> 4, tx = tid & 15;
  float acc[4][4];
  #pragma unroll
  for (int i = 0; i < 4; ++i)
    #pragma unroll
    for (int j = 0; j < 4; ++j) acc[i][j] = 0.f;

  for (int kb = 0; kb < 4; ++kb) {
    #pragma unroll
    for (int q = 0; q < 2; ++q) {
      int f4 = tid + 256*q;
      int r = f4 >> 3, cg = f4 & 7;
      float4 av = *(const float4*)&P.A[(size_t)(row0+r)*128 + kb*32 + cg*4];
      As[cg*4+0][r] = av.x; As[cg*4+1][r] = av.y; As[cg*4+2][r] = av.z; As[cg*4+3][r] = av.w;
    }
    #pragma unroll
    for (int q = 0; q < 2; ++q) {
      int f4 = tid + 256*q;
      int kr = f4 >> 4, cg = f4 & 15;
      *(float4*)&Bs[kr][cg*4] = *(const float4*)&W[(size_t)(kb*32+kr)*nc + col0 + cg*4];
    }
    __syncthreads();
    #pragma unroll
    for (int kk = 0; kk < 32; ++kk) {
      float4 a = *(float4*)&As[kk][ty*4];
      float4 b = *(float4*)&Bs[kk][tx*4];
      acc[0][0] += a.x*b.x; acc[0][1] += a.x*b.y; acc[0][2] += a.x*b.z; acc[0][3] += a.x*b.w;
      acc[1][0] += a.y*b.x; acc[1][1] += a.y*b.y; acc[1][2] += a.y*b.z; acc[1][3] += a.y*b.w;
      acc[2][0] += a.z*b.x; acc[2][1] += a.z*b.y; acc[2][2] += a.z*b.z; acc[2][3] += a.z*b.w;
      acc[3][0] += a.w*b.x; acc[3][1] += a.w*b.y; acc[3][2] += a.w*b.z; acc[3][3] += a.w*b.w;
    }
    __syncthreads();
  }
  #pragma unroll
  for (int i = 0; i < 4; ++i) {
    int rr = row0 + ty*4 + i;
    float mv = 0.f, mk = 0.f;
    if (act == 3) { mv = P.mval[rr]; mk = P.maskf[rr]; }
    #pragma unroll
    for (int j = 0; j < 4; ++j) {
      int cc = col0 + tx*4 + j;
      float v = acc[i][j];
      if (act == 1) v = fmaxf(v, 0.f);
      else if (act == 2) v += P.res[(size_t)rr*128 + cc];
      else if (act == 3) {
        float hl = P.res[(size_t)rr*128 + cc];
        v = (1.f - mv)*hl + mv*mk*(hl + v);
      }
      C[(size_t)rr*nc + cc] = v;
    }
  }
}

// =======================================================================
__global__ void hmp_mul_p1(const float* __restrict__ hv, const float* __restrict__ G,
                           float* __restrict__ P1) {
  int i = blockIdx.x * 256 + threadIdx.x;
  if (i >= NN*96) return;
  int n = i / 96, q = i - n*96, v = q / 3;
  P1[i] = hv[i] * G[(size_t)n*64 + v];
}

// hl_v = h_v + S1v(fx) ; P2 = hl_v * G2[:, :V]
__global__ void hmp_hlv_p2(const float* __restrict__ hv, const long long* __restrict__ accv,
                           const float* __restrict__ G2, float* __restrict__ hlv,
                           float* __restrict__ P2) {
  int i = blockIdx.x * 256 + threadIdx.x;
  if (i >= NN*96) return;
  int n = i / 96, q = i - n*96, v = q / 3;
  float x = hv[i] + fxToF(accv[i]);
  hlv[i] = x;
  P2[i] = x * G2[(size_t)n*64 + v];
}

// i64 fixed-point -> float conversion
__global__ void hmp_cvt(const long long* __restrict__ a, float* __restrict__ o, int n) {
  int i = blockIdx.x * 256 + threadIdx.x;
  if (i < n) o[i] = fxToF(a[i]);
}

// =======================================================================
// pass-1 (unmasked) real-edge messages — deterministic i64 fixed-point
__global__ void hmp_msg_s(const int* __restrict__ ei, const float* __restrict__ ln,
                          const float* __restrict__ R, long long* __restrict__ S) {
  int idx = blockIdx.x * 256 + threadIdx.x;
  int e = idx >> 7, c = idx & 127;
  int s = ei[e], d = ei[EE + e];
  atomAddFx(&S[(size_t)d*128 + c], ln[e] * R[(size_t)s*128 + c]);
}

__global__ void hmp_msg_v(const int* __restrict__ ei, const float* __restrict__ dirn,
                          const float* __restrict__ P, const float* __restrict__ G,
                          long long* __restrict__ Sv) {
  int idx = blockIdx.x * 256 + threadIdx.x;
  int e = idx / 96, q = idx - e*96;
  int v = q / 3, c = q - v*3;
  int s = ei[e], d = ei[EE + e];
  float msg = P[(size_t)s*96 + q] + dirn[(size_t)e*3 + c] * G[(size_t)s*64 + 32 + v];
  atomAddFx(&Sv[(size_t)d*96 + q], msg);
}

// pass-2: compacted master-edge list, grid-stride
__global__ void hmp_edge_compact(const int* __restrict__ ei, const float* __restrict__ maskf,
                                 int* __restrict__ medge, int* __restrict__ mecnt) {
  int e = blockIdx.x * 256 + threadIdx.x;
  if (e >= EE) return;
  if (maskf[ei[e]] > 0.f && maskf[ei[EE + e]] > 0.f) {
    int s = atomicAdd(mecnt, 1);
    medge[s] = e;
  }
}

__global__ void hmp_msg_s2(const int* __restrict__ medge, const int* __restrict__ mecnt,
                           const int* __restrict__ ei, const float* __restrict__ ln,
                           const float* __restrict__ R, long long* __restrict__ S) {
  int total = (*mecnt) << 7;
  for (int idx = blockIdx.x * 256 + threadIdx.x; idx < total; idx += gridDim.x * 256) {
    int e = medge[idx >> 7], c = idx & 127;
    int s = ei[e], d = ei[EE + e];
    atomAddFx(&S[(size_t)d*128 + c], ln[e] * R[(size_t)s*128 + c]);
  }
}

__global__ void hmp_msg_v2(const int* __restrict__ medge, const int* __restrict__ mecnt,
                           const int* __restrict__ ei, const float* __restrict__ dirn,
                           const float* __restrict__ P, const float* __restrict__ G,
                           long long* __restrict__ Sv) {
  int total = (*mecnt) * 96;
  for (int idx = blockIdx.x * 256 + threadIdx.x; idx < total; idx += gridDim.x * 256) {
    int eo = idx / 96, q = idx - eo*96;
    int v = q / 3, c = q - v*3;
    int e = medge[eo];
    int s = ei[e], d = ei[EE + e];
    float msg = P[(size_t)s*96 + q] + dirn[(size_t)e*3 + c] * G[(size_t)s*64 + 32 + v];
    atomAddFx(&Sv[(size_t)d*96 + q], msg);
  }
}

// =======================================================================
__global__ __launch_bounds__(256) void hmp_master(const float* __restrict__ hls,
                                                  const float* __restrict__ Wm1,
                                                  const float* __restrict__ bm1,
                                                  const float* __restrict__ Wm2,
                                                  const float* __restrict__ bm2,
                                                  float* __restrict__ mval,
                                                  float* __restrict__ maskf,
                                                  float* __restrict__ out_m) {
  __shared__ float sW[128*64];
  __shared__ float sx[4][128];
  int tid = threadIdx.x;
  for (int i = tid; i < 8192; i += 256) sW[i] = Wm1[i];
  for (int i = tid; i < 512; i += 256) {
    int nn = i >> 7;
    sx[nn][i & 127] = hls[(size_t)(blockIdx.x*4 + nn)*128 + (i & 127)];
  }
  __syncthreads();
  int nl = tid >> 6, lane = tid & 63;
  int n = blockIdx.x * 4 + nl;
  float h = bm1[lane];
  for (int k = 0; k < 128; ++k) h += sx[nl][k] * sW[k*64 + lane];
  h = fmaxf(h, 0.f) * Wm2[lane];
  for (int off = 32; off; off >>= 1) h += __shfl_down(h, off, 64);
  if (lane == 0) {
    float logit = h + bm2[0];
    float mv = 1.f / (1.f + expf(-logit));
    mval[n] = mv;
    maskf[n] = (mv > 0.5f) ? 1.f : 0.f;
    out_m[n] = mv;
  }
}

// order-preserving compaction of master indices (single block)
__global__ void hmp_compact(const float* __restrict__ maskf, int* __restrict__ midx,
                            int* __restrict__ nmp) {
  __shared__ int ls[256];
  int tid = threadIdx.x;
  int base = tid * 16;
  int cnt = 0;
  #pragma unroll
  for (int i = 0; i < 16; ++i) cnt += (maskf[base + i] > 0.f) ? 1 : 0;
  ls[tid] = cnt;
  __syncthreads();
  for (int off = 1; off < 256; off <<= 1) {
    int v = (tid >= off) ? ls[tid - off] : 0;
    __syncthreads();
    ls[tid] += v;
    __syncthreads();
  }
  int p = ls[tid] - cnt;
  for (int i = 0; i < 16; ++i)
    if (maskf[base + i] > 0.f) midx[p++] = base + i;
  if (tid == 255) *nmp = ls[255];
}

__global__ void hmp_colsum_w3(const float* __restrict__ Wa1, float* __restrict__ w3) {
  int s = threadIdx.x;
  float acc = 0.f;
  for (int k = 0; k < 128; ++k) acc += Wa1[(size_t)(256 + k)*128 + s];
  w3[s] = acc;
}

// =======================================================================
// compacted attention v3: 8 comp-rows/block, 1 row x 2 cols per lane,
// single top-8 list/lane, split-2 over K tiles for occupancy.
__global__ __launch_bounds__(256) void hmp_attn3(const float* __restrict__ Q,
                                                 const float* __restrict__ Kk,
                                                 const unsigned long long* __restrict__ adj,
                                                 const int* __restrict__ midx,
                                                 const int* __restrict__ nmp,
                                                 int2* __restrict__ pt) {
  const int nm = *nmp;
  const int rowblk = blockIdx.x >> 1;
  const int split  = blockIdx.x & 1;
  const int row0 = rowblk * 8;
  if (row0 >= nm) return;

  __shared__ float sQ[8][132];
  __shared__ float sK[64][132];
  __shared__ int   sCI[64];
  __shared__ int   sRI[8];
  __shared__ unsigned long long sAdj[8][64];

  const int tid = threadIdx.x;
  { // stage Q rows (gathered via midx): 8 rows x 32 float4 = 256
    int rr = tid >> 5, c = tid & 31;
    int gr = row0 + rr;
    int ri = (gr < nm) ? midx[gr] : -1;
    float4 v; v.x = v.y = v.z = v.w = 0.f;
    if (ri >= 0) v = *(const float4*)&Q[(size_t)ri*128 + c*4];
    *(float4*)&sQ[rr][c*4] = v;
  }
  if (tid < 8) sRI[tid] = (row0 + tid < nm) ? midx[row0 + tid] : -1;
  #pragma unroll
  for (int q = 0; q < 2; ++q) {  // 512 u64
    int i = tid + 256*q;
    int rr = i >> 6, w = i & 63;
    int gr = row0 + rr;
    int ri = (gr < nm) ? midx[gr] : -1;
    sAdj[rr][w] = (ri >= 0) ? adj[(size_t)ri*64 + w] : 0ULL;
  }

  const int ntiles = (nm + 63) >> 6;
  const int l = tid & 63, wv = tid >> 6;
  const int r = wv*2 + (l >> 5);          // lanes 0-31: row 2wv, 32-63: row 2wv+1
  const int c0 = l & 31, c1 = c0 + 32;

  float tv[8]; int tc[8];
  #pragma unroll
  for (int k = 0; k < 8; ++k) { tv[k] = -1.f; tc[k] = 0x7fffffff; }

  for (int t = split; t < ntiles; t += 2) {
    #pragma unroll
    for (int q = 0; q < 8; ++q) {  // 2048 float4
      int f4 = tid + 256*q;
      int rr = f4 >> 5, c = f4 & 31;
      int gc = t*64 + rr;
      int ci = (gc < nm) ? midx[gc] : -1;
      float4 v; v.x = v.y = v.z = v.w = 0.f;
      if (ci >= 0) v = *(const float4*)&Kk[(size_t)ci*128 + c*4];
      *(float4*)&sK[rr][c*4] = v;
    }
    if (tid < 64) sCI[tid] = (t*64 + tid < nm) ? midx[t*64 + tid] : -1;
    __syncthreads();

    float a0x=0,a0y=0,a0z=0,a0w=0, a1x=0,a1y=0,a1z=0,a1w=0;
    #pragma unroll
    for (int kk = 0; kk < 32; ++kk) {
      float4 qv = *(float4*)&sQ[r][kk*4];
      float4 k0 = *(float4*)&sK[c0][kk*4];
      float4 k1 = *(float4*)&sK[c1][kk*4];
      a0x += qv.x*k0.x; a0y += qv.y*k0.y; a0z += qv.z*k0.z; a0w += qv.w*k0.w;
      a1x += qv.x*k1.x; a1y += qv.y*k1.y; a1z += qv.z*k1.z; a1w += qv.w*k1.w;
    }
    float d0 = (a0x+a0y)+(a0z+a0w);
    float d1 = (a1x+a1y)+(a1z+a1w);

    const int ro = sRI[r];
    const int jo0 = sCI[c0], jo1 = sCI[c1];
    {
      bool ok = (jo0 >= 0) && (ro >= 0) && (jo0 != ro) &&
                !((sAdj[r][jo0 >> 6] >> (jo0 & 63)) & 1ULL);
      if (ok) {
        float z = d0 / 11.3137085f;
        float attn = 1.f / (1.f + expf(-z));
        INSERT8(tv, tc, attn, jo0);
      }
    }
    {
      bool ok = (jo1 >= 0) && (ro >= 0) && (jo1 != ro) &&
                !((sAdj[r][jo1 >> 6] >> (jo1 & 63)) & 1ULL);
      if (ok) {
        float z = d1 / 11.3137085f;
        float attn = 1.f / (1.f + expf(-z));
        INSERT8(tv, tc, attn, jo1);
      }
    }
    __syncthreads();
  }

  merge32(tv, tc);

  if ((l & 31) == 0) {
    int gr = row0 + r;
    #pragma unroll
    for (int k = 0; k < 8; ++k)
      pt[((size_t)gr*2 + split)*8 + k] = make_int2(__float_as_int(tv[k]), tc[k]);
  }
}

// merge 2 sorted split-lists per compacted row, threshold, emit edges
__global__ void hmp_topk_emit(const int2* __restrict__ pt, const int* __restrict__ midx,
                              const int* __restrict__ nmp, float* __restrict__ Avirt,
                              int2* __restrict__ vedges, int* __restrict__ vcnt) {
  int i = blockIdx.x * 256 + threadIdx.x;
  if (i >= *nmp) return;
  const int2* LA = pt + (size_t)i*16;
  const int2* LB = LA + 8;
  int a = 0, b = 0;
  int grow = midx[i];
  #pragma unroll
  for (int k = 0; k < 8; ++k) {
    int2 ca = LA[a];
    int2 cb = LB[b];
    float va = __int_as_float(ca.x), vb = __int_as_float(cb.x);
    bool pickA = (va > vb) || (va == vb && ca.y < cb.y);
    int2 sel = pickA ? ca : cb;
    if (pickA) ++a; else ++b;
    float v = __int_as_float(sel.x);
    if (v > 0.55f) {
      Avirt[(size_t)grow*NN + sel.y] = 1.f;
      int slot = atomicAdd(vcnt, 1);
      vedges[slot] = make_int2(grow, sel.y);
    }
  }
}

// =======================================================================
__global__ __launch_bounds__(256) void hmp_vedge_sc(const int2* __restrict__ ve,
                                                    const int* __restrict__ vcnt,
                                                    const float* __restrict__ pos,
                                                    const float* __restrict__ A1,
                                                    const float* __restrict__ A2,
                                                    const float* __restrict__ w3,
                                                    const float* __restrict__ ba1,
                                                    const float* __restrict__ Wa2,
                                                    const float* __restrict__ ba2,
                                                    float* __restrict__ lnv,
                                                    float* __restrict__ dirv,
                                                    float* __restrict__ sc,
                                                    unsigned int* __restrict__ mxenc) {
  int cnt = *vcnt;
  int lane = threadIdx.x & 63;
  for (int e = blockIdx.x * 4 + (threadIdx.x >> 6); e < cnt; e += gridDim.x * 4) {
    int2 ed = ve[e];
    int i = ed.x, j = ed.y;
    float vx = pos[i*3+0] - pos[j*3+0];
    float vy = pos[i*3+1] - pos[j*3+1];
    float vz = pos[i*3+2] - pos[j*3+2];
    float lval = sqrtf(vx*vx + vy*vy + vz*vz);
    float acc = 0.f;
    #pragma unroll
    for (int half = 0; half < 2; ++half) {
      int c = lane + half*64;
      float tq = A1[(size_t)i*128 + c] + A2[(size_t)j*128 + c] + lval*w3[c] + ba1[c];
      acc += fmaxf(tq, 0.f) * Wa2[c];
    }
    for (int off = 32; off; off >>= 1) acc += __shfl_down(acc, off, 64);
    if (lane == 0) {
      lnv[e] = lval;
      if (lval > 1e-12f) {
        dirv[e*3+0] = vx / lval; dirv[e*3+1] = vy / lval; dirv[e*3+2] = vz / lval;
      } else {
        dirv[e*3+0] = 0.f; dirv[e*3+1] = 0.f; dirv[e*3+2] = 0.f;
      }
      float s = acc + ba2[0];
      sc[e] = s;
      unsigned int bits = __float_as_uint(s);
      unsigned int enc = (bits & 0x80000000u) ? ~bits : (bits | 0x80000000u);
      atomicMax(&mxenc[j], enc);
    }
  }
}

__global__ void hmp_vexp(const int2* __restrict__ ve, const int* __restrict__ vcnt,
                         const float* __restrict__ sc, const unsigned int* __restrict__ mxenc,
                         float* __restrict__ eexp, long long* __restrict__ den64) {
  int cnt = *vcnt;
  for (int e = blockIdx.x * 256 + threadIdx.x; e < cnt; e += gridDim.x * 256) {
    int j = ve[e].y;
    unsigned int enc = mxenc[j];
    unsigned int bits = (enc & 0x80000000u) ? (enc & 0x7fffffffu) : ~enc;
    float mx = __uint_as_float(bits);
    float ex = expf(sc[e] - mx);
    eexp[e] = ex;
    atomAddFx(&den64[j], ex);
  }
}

__global__ void hmp_msgv_s(const int2* __restrict__ ve, const int* __restrict__ vcnt,
                           const float* __restrict__ eexp, const long long* __restrict__ den64,
                           const float* __restrict__ lnv, const float* __restrict__ R2,
                           long long* __restrict__ S2s) {
  int total = (*vcnt) << 7;
  for (int idx = blockIdx.x * 256 + threadIdx.x; idx < total; idx += gridDim.x * 256) {
    int e = idx >> 7, c = idx & 127;
    int2 ed = ve[e];
    float denf = fxToF(den64[ed.y]);
    float decay = eexp[e] / fmaxf(denf, 1e-9f);
    atomAddFx(&S2s[(size_t)ed.y*128 + c], lnv[e] * decay * R2[(size_t)ed.x*128 + c]);
  }
}

__global__ void hmp_msgv_v(const int2* __restrict__ ve, const int* __restrict__ vcnt,
                           const float* __restrict__ eexp, const long long* __restrict__ den64,
                           const float* __restrict__ dirv, const float* __restrict__ P2,
                           const float* __restrict__ G2, long long* __restrict__ S2v) {
  int total = (*vcnt) * 96;
  for (int idx = blockIdx.x * 256 + threadIdx.x; idx < total; idx += gridDim.x * 256) {
    int e = idx / 96, q = idx - e*96;
    int v = q / 3, c = q - v*3;
    int2 ed = ve[e];
    float denf = fxToF(den64[ed.y]);
    float decay = eexp[e] / fmaxf(denf, 1e-9f);
    float msg = P2[(size_t)ed.x*96 + q] + dirv[(size_t)e*3 + c] * decay * G2[(size_t)ed.x*64 + 32 + v];
    atomAddFx(&S2v[(size_t)ed.y*96 + q], msg);
  }
}

__global__ void hmp_final_v(const float* __restrict__ hlv, const long long* __restrict__ accv,
                            const float* __restrict__ mval, const float* __restrict__ maskf,
                            float* __restrict__ out) {
  int idx = blockIdx.x * 256 + threadIdx.x;
  if (idx >= NN*96) return;
  int n = idx / 96;
  float mv = mval[n], mk = maskf[n];
  float x = hlv[idx];
  out[idx] = (1.f - mv)*x + mv*mk*(x + fxToF(accv[idx]));
}

// =======================================================================
extern "C" void kernel_launch(void* const* d_in, const int* in_sizes, int n_in,
                              void* d_out, int out_size, void* d_ws, size_t ws_size,
                              hipStream_t stream) {
  const float* h_s = (const float*)d_in[0];
  const float* h_v = (const float*)d_in[1];
  const float* pos = (const float*)d_in[2];
  const int*   ei  = (const int*)d_in[3];
  const float* W1  = (const float*)d_in[5];
  const float* Wg  = (const float*)d_in[6];
  const float* W2  = (const float*)d_in[7];
  const float* Wm1 = (const float*)d_in[8];
  const float* bm1 = (const float*)d_in[9];
  const float* Wm2 = (const float*)d_in[10];
  const float* bm2 = (const float*)d_in[11];
  const float* Wq  = (const float*)d_in[12];
  const float* Wk  = (const float*)d_in[13];
  const float* Wa1 = (const float*)d_in[14];
  const float* ba1 = (const float*)d_in[15];
  const float* Wa2 = (const float*)d_in[16];
  const float* ba2 = (const float*)d_in[17];

  if (ws_size < OFF_END * sizeof(float)) return;

  float* ws  = (float*)d_ws;
  float* out = (float*)d_out;

  float* ln   = ws + OFF_LN;
  float* dirn = ws + OFF_DIRN;
  float* R    = ws + OFF_R;
  float* G    = ws + OFF_G;
  float* P1   = ws + OFF_P1;
  float* hls  = ws + OFF_HLS;
  float* hlv  = ws + OFF_HLV;
  float* mval = ws + OFF_MVAL;
  float* mskf = ws + OFF_MASK;
  float* Qb   = ws + OFF_Q;
  float* Kb   = ws + OFF_K;
  float* A1   = ws + OFF_A1;
  float* A2   = ws + OFF_A2;
  float* R2   = ws + OFF_R2;
  float* G2   = ws + OFF_G2;
  float* P2   = ws + OFF_P2;
  float* w3   = ws + OFF_W3;
  float* lnv  = ws + OFF_LNV;
  float* dirv = ws + OFF_DIRV;
  float* sc   = ws + OFF_SC;
  float* eexp = ws + OFF_EEXP;
  int2*  vedg = (int2*)(ws + OFF_VEDGE);
  int*   midx = (int*)(ws + OFF_MIDX);
  int2*  pt   = (int2*)(ws + OFF_PT);
  int*   medge= (int*)(ws + OFF_MEDGE);
  float* SF   = ws + OFF_SF;
  long long* accs  = (long long*)(ws + OFF_ACCS);
  long long* accv  = (long long*)(ws + OFF_ACCV);
  long long* den64 = (long long*)(ws + OFF_DEN64);
  unsigned int* mxenc = (unsigned int*)(ws + OFF_MX);
  unsigned long long* adj = (unsigned long long*)(ws + OFF_ADJ);
  int*   cnts = (int*)(ws + OFF_CNT);
  int*   vcnt = cnts + 0;
  int*   mecnt= cnts + 1;
  int*   nmp  = cnts + 2;

  // zero accumulators + counters + adjacency + A_virtual; copy pos through
  hipMemsetAsync(ws + OFF_ZBEG, 0, (OFF_END - OFF_ZBEG) * sizeof(float), stream);
  hipMemsetAsync(out + OUT_AV, 0, (size_t)NN * NN * sizeof(float), stream);
  hipMemcpyAsync(out + OUT_POS, pos, (size_t)NN * 3 * sizeof(float),
                 hipMemcpyDeviceToDevice, stream);

  hmp_edge_prep<<<EE/256, 256, 0, stream>>>(ei, pos, ln, dirn, adj);

  { // R = relu(h_s@W1), G = h_s@Wg
    GemmJobs J = {};
    J.A = h_s;
    J.W[0] = W1; J.C[0] = R; J.Nc[0] = 128; J.act[0] = 1;
    J.W[1] = Wg; J.C[1] = G; J.Nc[1] = 64;  J.act[1] = 0;
    hmp_gemm_k128<<<dim3(64,2,2), 256, 0, stream>>>(J);
  }
  hmp_mul_p1<<<NN*96/256, 256, 0, stream>>>(h_v, G, P1);
  hmp_msg_s<<<EE*128/256, 256, 0, stream>>>(ei, ln, R, accs);
  hmp_msg_v<<<EE*96/256, 256, 0, stream>>>(ei, dirn, P1, G, accv);

  hmp_cvt<<<NN*128/256, 256, 0, stream>>>(accs, SF, NN*128);
  { // hl_s = S1s@W2 + h_s
    GemmJobs J = {};
    J.A = SF; J.res = h_s;
    J.W[0] = W2; J.C[0] = hls; J.Nc[0] = 128; J.act[0] = 2;
    hmp_gemm_k128<<<dim3(64,2,1), 256, 0, stream>>>(J);
  }

  hmp_master<<<NN/4, 256, 0, stream>>>(hls, Wm1, bm1, Wm2, bm2, mval, mskf, out + OUT_M);
  hmp_compact<<<1, 256, 0, stream>>>(mskf, midx, nmp);

  { // Q, K, A1, A2, R2=relu(hl_s@W1), G2=hl_s@Wg
    GemmJobs J = {};
    J.A = hls;
    J.W[0] = Wq;          J.C[0] = Qb; J.Nc[0] = 128; J.act[0] = 0;
    J.W[1] = Wk;          J.C[1] = Kb; J.Nc[1] = 128; J.act[1] = 0;
    J.W[2] = Wa1;         J.C[2] = A1; J.Nc[2] = 128; J.act[2] = 0;
    J.W[3] = Wa1 + 16384; J.C[3] = A2; J.Nc[3] = 128; J.act[3] = 0;
    J.W[4] = W1;          J.C[4] = R2; J.Nc[4] = 128; J.act[4] = 1;
    J.W[5] = Wg;          J.C[5] = G2; J.Nc[5] = 64;  J.act[5] = 0;
    hmp_gemm_k128<<<dim3(64,2,6), 256, 0, stream>>>(J);
  }
  hmp_colsum_w3<<<1, 128, 0, stream>>>(Wa1, w3);
  hmp_hlv_p2<<<NN*96/256, 256, 0, stream>>>(h_v, accv, G2, hlv, P2);

  // re-zero i64 accumulators for pass-2 reuse (S1 consumers are done above)
  hipMemsetAsync(ws + OFF_ACCS, 0, (size_t)(NN*256 + NN*192) * sizeof(float), stream);

  hmp_attn3<<<(NN/8)*2, 256, 0, stream>>>(Qb, Kb, adj, midx, nmp, pt);
  hmp_topk_emit<<<NN/256, 256, 0, stream>>>(pt, midx, nmp, out + OUT_AV, vedg, vcnt);

  hmp_edge_compact<<<EE/256, 256, 0, stream>>>(ei, mskf, medge, mecnt);

  hmp_vedge_sc<<<512, 256, 0, stream>>>(vedg, vcnt, pos, A1, A2, w3, ba1, Wa2, ba2,
                                        lnv, dirv, sc, mxenc);
  hmp_vexp<<<128, 256, 0, stream>>>(vedg, vcnt, sc, mxenc, eexp, den64);

  hmp_msg_s2<<<2048, 256, 0, stream>>>(medge, mecnt, ei, ln, R2, accs);
  hmp_msg_v2<<<2048, 256, 0, stream>>>(medge, mecnt, ei, dirn, P2, G2, accv);
  hmp_msgv_s<<<1024, 256, 0, stream>>>(vedg, vcnt, eexp, den64, lnv, R2, accs);
  hmp_msgv_v<<<1024, 256, 0, stream>>>(vedg, vcnt, eexp, den64, dirv, P2, G2, accv);

  hmp_cvt<<<NN*128/256, 256, 0, stream>>>(accs, SF, NN*128);
  { // hf_s = (1-m)*hl_s + m*mask*(hl_s + S2s@W2)
    GemmJobs J = {};
    J.A = SF; J.res = hls; J.mval = mval; J.maskf = mskf;
    J.W[0] = W2; J.C[0] = out + OUT_HFS; J.Nc[0] = 128; J.act[0] = 3;
    hmp_gemm_k128<<<dim3(64,2,1), 256, 0, stream>>>(J);
  }
  hmp_final_v<<<NN*96/256, 256, 0, stream>>>(hlv, accv, mval, mskf, out + OUT_HFV);
}

// Round 5
// 475.389 us; speedup vs baseline: 1.4292x; 1.1430x over previous
//
#include <hip/hip_runtime.h>
#include <math.h>

#define NN 4096
#define EE 131072
#define NKMAX 32768

#define SCALE_FX 8388608.0      /* 2^23 fixed-point scale */
#define INV_FX   (1.0/8388608.0)

__device__ __forceinline__ void atomAddFx(long long* p, float v) {
  atomicAdd((unsigned long long*)p, (unsigned long long)llrint((double)v * SCALE_FX));
}
__device__ __forceinline__ long long toFx(float v) {
  return llrint((double)v * SCALE_FX);
}
__device__ __forceinline__ float fxToF(long long v) {
  return (float)((double)v * INV_FX);
}

// ---- workspace layout (float offsets) ----
#define OFF_LN    ((size_t)0)
#define OFF_DIRN  (OFF_LN + EE)
#define OFF_R     (OFF_DIRN + (size_t)EE*3)
#define OFF_G     (OFF_R + (size_t)NN*128)
#define OFF_P1    (OFF_G + (size_t)NN*64)
#define OFF_HLS   (OFF_P1 + (size_t)NN*96)
#define OFF_HLV   (OFF_HLS + (size_t)NN*128)
#define OFF_MVAL  (OFF_HLV + (size_t)NN*96)
#define OFF_MASK  (OFF_MVAL + NN)
#define OFF_Q     (OFF_MASK + NN)
#define OFF_K     (OFF_Q + (size_t)NN*128)
#define OFF_A1    (OFF_K + (size_t)NN*128)
#define OFF_A2    (OFF_A1 + (size_t)NN*128)
#define OFF_R2    (OFF_A2 + (size_t)NN*128)
#define OFF_G2    (OFF_R2 + (size_t)NN*128)
#define OFF_P2    (OFF_G2 + (size_t)NN*64)
#define OFF_W3    (OFF_P2 + (size_t)NN*96)
#define OFF_LNV   (OFF_W3 + 128)
#define OFF_DIRV  (OFF_LNV + NKMAX)
#define OFF_SC    (OFF_DIRV + (size_t)NKMAX*3)
#define OFF_EEXP  (OFF_SC + NKMAX)
#define OFF_VEDGE (OFF_EEXP + NKMAX)
#define OFF_MIDX  (OFF_VEDGE + (size_t)NKMAX*2)
#define OFF_PT    (OFF_MIDX + NN)              /* int2[NN*16] = NN*32 floats */
#define OFF_CSR   (OFF_PT + (size_t)NN*32)     /* int[EE] dst-sorted edge ids */
#define OFF_ROWPT (OFF_CSR + EE)               /* int[NN+1] */
#define OFF_CURS  (OFF_ROWPT + NN + 64)        /* int[NN] */
#define OFF_S1S   (OFF_CURS + NN)              /* float[NN*128] */
#define OFF_S1V   (OFF_S1S + (size_t)NN*128)   /* float[NN*96] */
/* overlays: R dead after pass-1 msg_s; P1 dead after pass-1 msg_v */
#define OFF_S2S   OFF_R                        /* float[NN*128] */
#define OFF_S2V   OFF_P1                       /* float[NN*96] */
#define OFF_ZBEG  (OFF_S1V + (size_t)NN*96)
#define OFF_CNTH  (OFF_ZBEG)                   /* int[NN] dst histogram */
#define OFF_ACCS  (OFF_CNTH + NN)              /* i64[NN*128] virtual scalar accum */
#define OFF_ACCV  (OFF_ACCS + (size_t)NN*256)  /* i64[NN*96] virtual vector accum */
#define OFF_DEN64 (OFF_ACCV + (size_t)NN*192)  /* i64[NN] softmax denom */
#define OFF_MX    (OFF_DEN64 + (size_t)NN*2)
#define OFF_ADJ   (OFF_MX + NN)                /* u64[NN*64] adjacency bitset */
#define OFF_CNT   (OFF_ADJ + (size_t)NN*128)   /* [0]=vcnt [2]=nm */
#define OFF_END   (OFF_CNT + 64)

// ---- output layout (float offsets) ----
#define OUT_HFS 0
#define OUT_HFV 524288
#define OUT_POS 917504
#define OUT_AV  929792
#define OUT_M   17707008

// exact stable insert into sorted-desc 8-list; requires ascending idx stream
#define INSERT8(TV, TC, VAL, IDX) do { \
  if ((VAL) > TV[7]) { \
    _Pragma("unroll") \
    for (int k_ = 7; k_ >= 1; --k_) { \
      bool gtk_ = (VAL) > TV[k_]; bool gtm_ = (VAL) > TV[k_-1]; \
      float nv_ = gtk_ ? (gtm_ ? TV[k_-1] : (VAL)) : TV[k_]; \
      int   ni_ = gtk_ ? (gtm_ ? TC[k_-1] : (IDX)) : TC[k_]; \
      TV[k_] = nv_; TC[k_] = ni_; } \
    bool gt0_ = (VAL) > TV[0]; \
    TV[0] = gt0_ ? (VAL) : TV[0]; TC[0] = gt0_ ? (IDX) : TC[0]; \
  } } while (0)

// butterfly merge of 32 per-lane sorted-8 lists within each 32-lane half
__device__ __forceinline__ void merge32(float (&tv)[8], int (&tc)[8]) {
  #pragma unroll
  for (int m = 1; m <= 16; m <<= 1) {
    float av[16]; int ac[16];
    #pragma unroll
    for (int k = 0; k < 8; ++k) { av[k] = tv[k]; ac[k] = tc[k]; }
    #pragma unroll
    for (int k = 0; k < 8; ++k) {
      av[8+k] = __shfl_xor(tv[7-k], m, 64);
      ac[8+k] = __shfl_xor(tc[7-k], m, 64);
    }
    #pragma unroll
    for (int d = 8; d >= 1; d >>= 1) {
      #pragma unroll
      for (int i = 0; i < 16; ++i) {
        if ((i & d) == 0) {
          const int jx = i + d;
          if (jx < 16) {
            bool sw = (av[i] < av[jx]) || (av[i] == av[jx] && ac[i] > ac[jx]);
            float t1 = sw ? av[jx] : av[i]; float t2 = sw ? av[i] : av[jx];
            int   u1 = sw ? ac[jx] : ac[i]; int   u2 = sw ? ac[i] : ac[jx];
            av[i] = t1; av[jx] = t2; ac[i] = u1; ac[jx] = u2;
          }
        }
      }
    }
    #pragma unroll
    for (int k = 0; k < 8; ++k) { tv[k] = av[k]; tc[k] = ac[k]; }
  }
}

// =======================================================================
// edge prep: ln, dirn, adjacency bitset, dst histogram
__global__ void hmp_edge_prep(const int* __restrict__ ei, const float* __restrict__ pos,
                              float* __restrict__ ln, float* __restrict__ dirn,
                              unsigned long long* __restrict__ adj,
                              int* __restrict__ cnth) {
  int e = blockIdx.x * 256 + threadIdx.x;
  if (e >= EE) return;
  int s = ei[e], d = ei[EE + e];
  float vx = pos[s*3+0] - pos[d*3+0];
  float vy = pos[s*3+1] - pos[d*3+1];
  float vz = pos[s*3+2] - pos[d*3+2];
  float l = sqrtf(vx*vx + vy*vy + vz*vz);
  ln[e] = l;
  if (l > 1e-12f) {
    dirn[e*3+0] = vx / l; dirn[e*3+1] = vy / l; dirn[e*3+2] = vz / l;
  } else {
    dirn[e*3+0] = 0.f; dirn[e*3+1] = 0.f; dirn[e*3+2] = 0.f;
  }
  atomicOr(&adj[(size_t)s*64 + (d >> 6)], 1ULL << (d & 63));
  atomicAdd(&cnth[d], 1);
}

// single-block exclusive scan of histogram -> rowptr, cursor
__global__ void hmp_csr_scan(const int* __restrict__ cnth, int* __restrict__ rowptr,
                             int* __restrict__ cursor) {
  __shared__ int ls[256];
  int tid = threadIdx.x;
  int base = tid * 16;
  int loc[16];
  int s = 0;
  #pragma unroll
  for (int i = 0; i < 16; ++i) { loc[i] = s; s += cnth[base + i]; }
  ls[tid] = s;
  __syncthreads();
  for (int off = 1; off < 256; off <<= 1) {
    int v = (tid >= off) ? ls[tid - off] : 0;
    __syncthreads();
    ls[tid] += v;
    __syncthreads();
  }
  int p = ls[tid] - s;
  #pragma unroll
  for (int i = 0; i < 16; ++i) {
    int rp = p + loc[i];
    rowptr[base + i] = rp;
    cursor[base + i] = rp;
  }
  if (tid == 255) rowptr[NN] = ls[255];
}

__global__ void hmp_csr_scatter(const int* __restrict__ ei, int* __restrict__ cursor,
                                int* __restrict__ csr) {
  int e = blockIdx.x * 256 + threadIdx.x;
  if (e >= EE) return;
  int d = ei[EE + e];
  int p = atomicAdd(&cursor[d], 1);
  csr[p] = e;
}

// =======================================================================
struct GemmJobs {
  const float* A;
  const float* W[6];
  float* C[6];
  int Nc[6];
  int act[6];       // 0 none, 1 relu, 2 +res, 3 final_s blend
  const float* res;
  const float* mval;
  const float* maskf;
};

__global__ __launch_bounds__(256) void hmp_gemm_k128(GemmJobs P) {
  const int g = blockIdx.z;
  const int nc = P.Nc[g];
  if ((int)blockIdx.y * 64 >= nc) return;
  const float* __restrict__ W = P.W[g];
  float* __restrict__ C = P.C[g];
  const int act = P.act[g];
  __shared__ float As[32][68];
  __shared__ float Bs[32][64];
  const int tid = threadIdx.x;
  const int row0 = blockIdx.x * 64, col0 = blockIdx.y * 64;
  const int ty = tid >> 4, tx = tid & 15;
  float acc[4][4];
  #pragma unroll
  for (int i = 0; i < 4; ++i)
    #pragma unroll
    for (int j = 0; j < 4; ++j) acc[i][j] = 0.f;

  for (int kb = 0; kb < 4; ++kb) {
    #pragma unroll
    for (int q = 0; q < 2; ++q) {
      int f4 = tid + 256*q;
      int r = f4 >> 3, cg = f4 & 7;
      float4 av = *(const float4*)&P.A[(size_t)(row0+r)*128 + kb*32 + cg*4];
      As[cg*4+0][r] = av.x; As[cg*4+1][r] = av.y; As[cg*4+2][r] = av.z; As[cg*4+3][r] = av.w;
    }
    #pragma unroll
    for (int q = 0; q < 2; ++q) {
      int f4 = tid + 256*q;
      int kr = f4 >> 4, cg = f4 & 15;
      *(float4*)&Bs[kr][cg*4] = *(const float4*)&W[(size_t)(kb*32+kr)*nc + col0 + cg*4];
    }
    __syncthreads();
    #pragma unroll
    for (int kk = 0; kk < 32; ++kk) {
      float4 a = *(float4*)&As[kk][ty*4];
      float4 b = *(float4*)&Bs[kk][tx*4];
      acc[0][0] += a.x*b.x; acc[0][1] += a.x*b.y; acc[0][2] += a.x*b.z; acc[0][3] += a.x*b.w;
      acc[1][0] += a.y*b.x; acc[1][1] += a.y*b.y; acc[1][2] += a.y*b.z; acc[1][3] += a.y*b.w;
      acc[2][0] += a.z*b.x; acc[2][1] += a.z*b.y; acc[2][2] += a.z*b.z; acc[2][3] += a.z*b.w;
      acc[3][0] += a.w*b.x; acc[3][1] += a.w*b.y; acc[3][2] += a.w*b.z; acc[3][3] += a.w*b.w;
    }
    __syncthreads();
  }
  #pragma unroll
  for (int i = 0; i < 4; ++i) {
    int rr = row0 + ty*4 + i;
    float mv = 0.f, mk = 0.f;
    if (act == 3) { mv = P.mval[rr]; mk = P.maskf[rr]; }
    #pragma unroll
    for (int j = 0; j < 4; ++j) {
      int cc = col0 + tx*4 + j;
      float v = acc[i][j];
      if (act == 1) v = fmaxf(v, 0.f);
      else if (act == 2) v += P.res[(size_t)rr*128 + cc];
      else if (act == 3) {
        float hl = P.res[(size_t)rr*128 + cc];
        v = (1.f - mv)*hl + mv*mk*(hl + v);
      }
      C[(size_t)rr*nc + cc] = v;
    }
  }
}

// =======================================================================
__global__ void hmp_mul_p1(const float* __restrict__ hv, const float* __restrict__ G,
                           float* __restrict__ P1) {
  int i = blockIdx.x * 256 + threadIdx.x;
  if (i >= NN*96) return;
  int n = i / 96, q = i - n*96, v = q / 3;
  P1[i] = hv[i] * G[(size_t)n*64 + v];
}

// hl_v = h_v + S1v ; P2 = hl_v * G2[:, :V]
__global__ void hmp_hlv_p2(const float* __restrict__ hv, const float* __restrict__ S1v,
                           const float* __restrict__ G2, float* __restrict__ hlv,
                           float* __restrict__ P2) {
  int i = blockIdx.x * 256 + threadIdx.x;
  if (i >= NN*96) return;
  int n = i / 96, q = i - n*96, v = q / 3;
  float x = hv[i] + S1v[i];
  hlv[i] = x;
  P2[i] = x * G2[(size_t)n*64 + v];
}

// =======================================================================
// CSR gather messages: one wave per dst, register i64 fx accumulation
// (order-independent exact sums -> deterministic), one float write.
__global__ __launch_bounds__(256) void hmp_csr_msg_s(
    const int* __restrict__ csr, const int* __restrict__ rowptr,
    const int* __restrict__ ei, const float* __restrict__ ln,
    const float* __restrict__ R, const float* __restrict__ maskf,
    float* __restrict__ S) {
  int d = blockIdx.x * 4 + (threadIdx.x >> 6);
  int l = threadIdx.x & 63;
  if (d >= NN) return;
  long long a0 = 0, a1 = 0;
  if (!maskf || maskf[d] > 0.f) {
    int k1 = rowptr[d + 1];
    for (int k = rowptr[d]; k < k1; ++k) {
      int e = csr[k];
      int s = ei[e];
      if (maskf && maskf[s] == 0.f) continue;
      float w = ln[e];
      a0 += toFx(w * R[(size_t)s*128 + l]);
      a1 += toFx(w * R[(size_t)s*128 + 64 + l]);
    }
  }
  S[(size_t)d*128 + l]      = fxToF(a0);
  S[(size_t)d*128 + 64 + l] = fxToF(a1);
}

__global__ __launch_bounds__(256) void hmp_csr_msg_v(
    const int* __restrict__ csr, const int* __restrict__ rowptr,
    const int* __restrict__ ei, const float* __restrict__ dirn,
    const float* __restrict__ P, const float* __restrict__ G,
    const float* __restrict__ maskf, float* __restrict__ Sv) {
  int d = blockIdx.x * 4 + (threadIdx.x >> 6);
  int l = threadIdx.x & 63;
  if (d >= NN) return;
  const int v0 = l / 3, c0 = l - v0*3;
  const int q1 = 64 + l, v1 = q1 / 3, c1 = q1 - v1*3;   // used when l<32
  long long a0 = 0, a1 = 0;
  if (!maskf || maskf[d] > 0.f) {
    int k1 = rowptr[d + 1];
    for (int k = rowptr[d]; k < k1; ++k) {
      int e = csr[k];
      int s = ei[e];
      if (maskf && maskf[s] == 0.f) continue;
      float m0 = P[(size_t)s*96 + l] + dirn[(size_t)e*3 + c0] * G[(size_t)s*64 + 32 + v0];
      a0 += toFx(m0);
      if (l < 32) {
        float m1 = P[(size_t)s*96 + q1] + dirn[(size_t)e*3 + c1] * G[(size_t)s*64 + 32 + v1];
        a1 += toFx(m1);
      }
    }
  }
  Sv[(size_t)d*96 + l] = fxToF(a0);
  if (l < 32) Sv[(size_t)d*96 + q1] = fxToF(a1);
}

// =======================================================================
__global__ __launch_bounds__(256) void hmp_master(const float* __restrict__ hls,
                                                  const float* __restrict__ Wm1,
                                                  const float* __restrict__ bm1,
                                                  const float* __restrict__ Wm2,
                                                  const float* __restrict__ bm2,
                                                  float* __restrict__ mval,
                                                  float* __restrict__ maskf,
                                                  float* __restrict__ out_m) {
  __shared__ float sW[128*64];
  __shared__ float sx[4][128];
  int tid = threadIdx.x;
  for (int i = tid; i < 8192; i += 256) sW[i] = Wm1[i];
  for (int i = tid; i < 512; i += 256) {
    int nn = i >> 7;
    sx[nn][i & 127] = hls[(size_t)(blockIdx.x*4 + nn)*128 + (i & 127)];
  }
  __syncthreads();
  int nl = tid >> 6, lane = tid & 63;
  int n = blockIdx.x * 4 + nl;
  float h = bm1[lane];
  for (int k = 0; k < 128; ++k) h += sx[nl][k] * sW[k*64 + lane];
  h = fmaxf(h, 0.f) * Wm2[lane];
  for (int off = 32; off; off >>= 1) h += __shfl_down(h, off, 64);
  if (lane == 0) {
    float logit = h + bm2[0];
    float mv = 1.f / (1.f + expf(-logit));
    mval[n] = mv;
    maskf[n] = (mv > 0.5f) ? 1.f : 0.f;
    out_m[n] = mv;
  }
}

// order-preserving compaction of master indices (single block)
__global__ void hmp_compact(const float* __restrict__ maskf, int* __restrict__ midx,
                            int* __restrict__ nmp) {
  __shared__ int ls[256];
  int tid = threadIdx.x;
  int base = tid * 16;
  int cnt = 0;
  #pragma unroll
  for (int i = 0; i < 16; ++i) cnt += (maskf[base + i] > 0.f) ? 1 : 0;
  ls[tid] = cnt;
  __syncthreads();
  for (int off = 1; off < 256; off <<= 1) {
    int v = (tid >= off) ? ls[tid - off] : 0;
    __syncthreads();
    ls[tid] += v;
    __syncthreads();
  }
  int p = ls[tid] - cnt;
  for (int i = 0; i < 16; ++i)
    if (maskf[base + i] > 0.f) midx[p++] = base + i;
  if (tid == 255) *nmp = ls[255];
}

__global__ void hmp_colsum_w3(const float* __restrict__ Wa1, float* __restrict__ w3) {
  int s = threadIdx.x;
  float acc = 0.f;
  for (int k = 0; k < 128; ++k) acc += Wa1[(size_t)(256 + k)*128 + s];
  w3[s] = acc;
}

// =======================================================================
// compacted attention: 8 comp-rows/block, 1 row x 2 cols per lane,
// single top-8 list/lane, split-2 over K tiles.
__global__ __launch_bounds__(256) void hmp_attn3(const float* __restrict__ Q,
                                                 const float* __restrict__ Kk,
                                                 const unsigned long long* __restrict__ adj,
                                                 const int* __restrict__ midx,
                                                 const int* __restrict__ nmp,
                                                 int2* __restrict__ pt) {
  const int nm = *nmp;
  const int rowblk = blockIdx.x >> 1;
  const int split  = blockIdx.x & 1;
  const int row0 = rowblk * 8;
  if (row0 >= nm) return;

  __shared__ float sQ[8][132];
  __shared__ float sK[64][132];
  __shared__ int   sCI[64];
  __shared__ int   sRI[8];
  __shared__ unsigned long long sAdj[8][64];

  const int tid = threadIdx.x;
  {
    int rr = tid >> 5, c = tid & 31;
    int gr = row0 + rr;
    int ri = (gr < nm) ? midx[gr] : -1;
    float4 v; v.x = v.y = v.z = v.w = 0.f;
    if (ri >= 0) v = *(const float4*)&Q[(size_t)ri*128 + c*4];
    *(float4*)&sQ[rr][c*4] = v;
  }
  if (tid < 8) sRI[tid] = (row0 + tid < nm) ? midx[row0 + tid] : -1;
  #pragma unroll
  for (int q = 0; q < 2; ++q) {
    int i = tid + 256*q;
    int rr = i >> 6, w = i & 63;
    int gr = row0 + rr;
    int ri = (gr < nm) ? midx[gr] : -1;
    sAdj[rr][w] = (ri >= 0) ? adj[(size_t)ri*64 + w] : 0ULL;
  }

  const int ntiles = (nm + 63) >> 6;
  const int l = tid & 63, wv = tid >> 6;
  const int r = wv*2 + (l >> 5);
  const int c0 = l & 31, c1 = c0 + 32;

  float tv[8]; int tc[8];
  #pragma unroll
  for (int k = 0; k < 8; ++k) { tv[k] = -1.f; tc[k] = 0x7fffffff; }

  for (int t = split; t < ntiles; t += 2) {
    #pragma unroll
    for (int q = 0; q < 8; ++q) {
      int f4 = tid + 256*q;
      int rr = f4 >> 5, c = f4 & 31;
      int gc = t*64 + rr;
      int ci = (gc < nm) ? midx[gc] : -1;
      float4 v; v.x = v.y = v.z = v.w = 0.f;
      if (ci >= 0) v = *(const float4*)&Kk[(size_t)ci*128 + c*4];
      *(float4*)&sK[rr][c*4] = v;
    }
    if (tid < 64) sCI[tid] = (t*64 + tid < nm) ? midx[t*64 + tid] : -1;
    __syncthreads();

    float a0x=0,a0y=0,a0z=0,a0w=0, a1x=0,a1y=0,a1z=0,a1w=0;
    #pragma unroll
    for (int kk = 0; kk < 32; ++kk) {
      float4 qv = *(float4*)&sQ[r][kk*4];
      float4 k0 = *(float4*)&sK[c0][kk*4];
      float4 k1 = *(float4*)&sK[c1][kk*4];
      a0x += qv.x*k0.x; a0y += qv.y*k0.y; a0z += qv.z*k0.z; a0w += qv.w*k0.w;
      a1x += qv.x*k1.x; a1y += qv.y*k1.y; a1z += qv.z*k1.z; a1w += qv.w*k1.w;
    }
    float d0 = (a0x+a0y)+(a0z+a0w);
    float d1 = (a1x+a1y)+(a1z+a1w);

    const int ro = sRI[r];
    const int jo0 = sCI[c0], jo1 = sCI[c1];
    {
      bool ok = (jo0 >= 0) && (ro >= 0) && (jo0 != ro) &&
                !((sAdj[r][jo0 >> 6] >> (jo0 & 63)) & 1ULL);
      if (ok) {
        float z = d0 / 11.3137085f;
        float attn = 1.f / (1.f + expf(-z));
        INSERT8(tv, tc, attn, jo0);
      }
    }
    {
      bool ok = (jo1 >= 0) && (ro >= 0) && (jo1 != ro) &&
                !((sAdj[r][jo1 >> 6] >> (jo1 & 63)) & 1ULL);
      if (ok) {
        float z = d1 / 11.3137085f;
        float attn = 1.f / (1.f + expf(-z));
        INSERT8(tv, tc, attn, jo1);
      }
    }
    __syncthreads();
  }

  merge32(tv, tc);

  if ((l & 31) == 0) {
    int gr = row0 + r;
    #pragma unroll
    for (int k = 0; k < 8; ++k)
      pt[((size_t)gr*2 + split)*8 + k] = make_int2(__float_as_int(tv[k]), tc[k]);
  }
}

// merge 2 sorted split-lists per compacted row, threshold, emit edges
__global__ void hmp_topk_emit(const int2* __restrict__ pt, const int* __restrict__ midx,
                              const int* __restrict__ nmp, float* __restrict__ Avirt,
                              int2* __restrict__ vedges, int* __restrict__ vcnt) {
  int i = blockIdx.x * 256 + threadIdx.x;
  if (i >= *nmp) return;
  const int2* LA = pt + (size_t)i*16;
  const int2* LB = LA + 8;
  int a = 0, b = 0;
  int grow = midx[i];
  #pragma unroll
  for (int k = 0; k < 8; ++k) {
    int2 ca = LA[a];
    int2 cb = LB[b];
    float va = __int_as_float(ca.x), vb = __int_as_float(cb.x);
    bool pickA = (va > vb) || (va == vb && ca.y < cb.y);
    int2 sel = pickA ? ca : cb;
    if (pickA) ++a; else ++b;
    float v = __int_as_float(sel.x);
    if (v > 0.55f) {
      Avirt[(size_t)grow*NN + sel.y] = 1.f;
      int slot = atomicAdd(vcnt, 1);
      vedges[slot] = make_int2(grow, sel.y);
    }
  }
}

// =======================================================================
__global__ __launch_bounds__(256) void hmp_vedge_sc(const int2* __restrict__ ve,
                                                    const int* __restrict__ vcnt,
                                                    const float* __restrict__ pos,
                                                    const float* __restrict__ A1,
                                                    const float* __restrict__ A2,
                                                    const float* __restrict__ w3,
                                                    const float* __restrict__ ba1,
                                                    const float* __restrict__ Wa2,
                                                    const float* __restrict__ ba2,
                                                    float* __restrict__ lnv,
                                                    float* __restrict__ dirv,
                                                    float* __restrict__ sc,
                                                    unsigned int* __restrict__ mxenc) {
  int cnt = *vcnt;
  int lane = threadIdx.x & 63;
  for (int e = blockIdx.x * 4 + (threadIdx.x >> 6); e < cnt; e += gridDim.x * 4) {
    int2 ed = ve[e];
    int i = ed.x, j = ed.y;
    float vx = pos[i*3+0] - pos[j*3+0];
    float vy = pos[i*3+1] - pos[j*3+1];
    float vz = pos[i*3+2] - pos[j*3+2];
    float lval = sqrtf(vx*vx + vy*vy + vz*vz);
    float acc = 0.f;
    #pragma unroll
    for (int half = 0; half < 2; ++half) {
      int c = lane + half*64;
      float tq = A1[(size_t)i*128 + c] + A2[(size_t)j*128 + c] + lval*w3[c] + ba1[c];
      acc += fmaxf(tq, 0.f) * Wa2[c];
    }
    for (int off = 32; off; off >>= 1) acc += __shfl_down(acc, off, 64);
    if (lane == 0) {
      lnv[e] = lval;
      if (lval > 1e-12f) {
        dirv[e*3+0] = vx / lval; dirv[e*3+1] = vy / lval; dirv[e*3+2] = vz / lval;
      } else {
        dirv[e*3+0] = 0.f; dirv[e*3+1] = 0.f; dirv[e*3+2] = 0.f;
      }
      float s = acc + ba2[0];
      sc[e] = s;
      unsigned int bits = __float_as_uint(s);
      unsigned int enc = (bits & 0x80000000u) ? ~bits : (bits | 0x80000000u);
      atomicMax(&mxenc[j], enc);
    }
  }
}

__global__ void hmp_vexp(const int2* __restrict__ ve, const int* __restrict__ vcnt,
                         const float* __restrict__ sc, const unsigned int* __restrict__ mxenc,
                         float* __restrict__ eexp, long long* __restrict__ den64) {
  int cnt = *vcnt;
  for (int e = blockIdx.x * 256 + threadIdx.x; e < cnt; e += gridDim.x * 256) {
    int j = ve[e].y;
    unsigned int enc = mxenc[j];
    unsigned int bits = (enc & 0x80000000u) ? (enc & 0x7fffffffu) : ~enc;
    float mx = __uint_as_float(bits);
    float ex = expf(sc[e] - mx);
    eexp[e] = ex;
    atomAddFx(&den64[j], ex);
  }
}

__global__ void hmp_msgv_s(const int2* __restrict__ ve, const int* __restrict__ vcnt,
                           const float* __restrict__ eexp, const long long* __restrict__ den64,
                           const float* __restrict__ lnv, const float* __restrict__ R2,
                           long long* __restrict__ acc) {
  int total = (*vcnt) << 7;
  for (int idx = blockIdx.x * 256 + threadIdx.x; idx < total; idx += gridDim.x * 256) {
    int e = idx >> 7, c = idx & 127;
    int2 ed = ve[e];
    float denf = fxToF(den64[ed.y]);
    float decay = eexp[e] / fmaxf(denf, 1e-9f);
    atomAddFx(&acc[(size_t)ed.y*128 + c], lnv[e] * decay * R2[(size_t)ed.x*128 + c]);
  }
}

__global__ void hmp_msgv_v(const int2* __restrict__ ve, const int* __restrict__ vcnt,
                           const float* __restrict__ eexp, const long long* __restrict__ den64,
                           const float* __restrict__ dirv, const float* __restrict__ P2,
                           const float* __restrict__ G2, long long* __restrict__ acc) {
  int total = (*vcnt) * 96;
  for (int idx = blockIdx.x * 256 + threadIdx.x; idx < total; idx += gridDim.x * 256) {
    int e = idx / 96, q = idx - e*96;
    int v = q / 3, c = q - v*3;
    int2 ed = ve[e];
    float denf = fxToF(den64[ed.y]);
    float decay = eexp[e] / fmaxf(denf, 1e-9f);
    float msg = P2[(size_t)ed.x*96 + q] + dirv[(size_t)e*3 + c] * decay * G2[(size_t)ed.x*64 + 32 + v];
    atomAddFx(&acc[(size_t)ed.y*96 + q], msg);
  }
}

// S2s += fx(virtual scalar accum)
__global__ void hmp_comb(float* __restrict__ S, const long long* __restrict__ acc, int n) {
  int i = blockIdx.x * 256 + threadIdx.x;
  if (i < n) S[i] += fxToF(acc[i]);
}

// final vector blend (+ virtual vector accum)
__global__ void hmp_final_v(const float* __restrict__ hlv, const float* __restrict__ S2v,
                            const long long* __restrict__ accv,
                            const float* __restrict__ mval, const float* __restrict__ maskf,
                            float* __restrict__ out) {
  int idx = blockIdx.x * 256 + threadIdx.x;
  if (idx >= NN*96) return;
  int n = idx / 96;
  float mv = mval[n], mk = maskf[n];
  float x = hlv[idx];
  out[idx] = (1.f - mv)*x + mv*mk*(x + S2v[idx] + fxToF(accv[idx]));
}

// =======================================================================
extern "C" void kernel_launch(void* const* d_in, const int* in_sizes, int n_in,
                              void* d_out, int out_size, void* d_ws, size_t ws_size,
                              hipStream_t stream) {
  const float* h_s = (const float*)d_in[0];
  const float* h_v = (const float*)d_in[1];
  const float* pos = (const float*)d_in[2];
  const int*   ei  = (const int*)d_in[3];
  const float* W1  = (const float*)d_in[5];
  const float* Wg  = (const float*)d_in[6];
  const float* W2  = (const float*)d_in[7];
  const float* Wm1 = (const float*)d_in[8];
  const float* bm1 = (const float*)d_in[9];
  const float* Wm2 = (const float*)d_in[10];
  const float* bm2 = (const float*)d_in[11];
  const float* Wq  = (const float*)d_in[12];
  const float* Wk  = (const float*)d_in[13];
  const float* Wa1 = (const float*)d_in[14];
  const float* ba1 = (const float*)d_in[15];
  const float* Wa2 = (const float*)d_in[16];
  const float* ba2 = (const float*)d_in[17];

  if (ws_size < OFF_END * sizeof(float)) return;

  float* ws  = (float*)d_ws;
  float* out = (float*)d_out;

  float* ln   = ws + OFF_LN;
  float* dirn = ws + OFF_DIRN;
  float* R    = ws + OFF_R;
  float* G    = ws + OFF_G;
  float* P1   = ws + OFF_P1;
  float* hls  = ws + OFF_HLS;
  float* hlv  = ws + OFF_HLV;
  float* mval = ws + OFF_MVAL;
  float* mskf = ws + OFF_MASK;
  float* Qb   = ws + OFF_Q;
  float* Kb   = ws + OFF_K;
  float* A1   = ws + OFF_A1;
  float* A2   = ws + OFF_A2;
  float* R2   = ws + OFF_R2;
  float* G2   = ws + OFF_G2;
  float* P2   = ws + OFF_P2;
  float* w3   = ws + OFF_W3;
  float* lnv  = ws + OFF_LNV;
  float* dirv = ws + OFF_DIRV;
  float* sc   = ws + OFF_SC;
  float* eexp = ws + OFF_EEXP;
  int2*  vedg = (int2*)(ws + OFF_VEDGE);
  int*   midx = (int*)(ws + OFF_MIDX);
  int2*  pt   = (int2*)(ws + OFF_PT);
  int*   csr  = (int*)(ws + OFF_CSR);
  int*   rowp = (int*)(ws + OFF_ROWPT);
  int*   curs = (int*)(ws + OFF_CURS);
  float* S1s  = ws + OFF_S1S;
  float* S1v  = ws + OFF_S1V;
  float* S2s  = ws + OFF_S2S;   // overlays R
  float* S2v  = ws + OFF_S2V;   // overlays P1
  int*   cnth = (int*)(ws + OFF_CNTH);
  long long* accs  = (long long*)(ws + OFF_ACCS);
  long long* accv  = (long long*)(ws + OFF_ACCV);
  long long* den64 = (long long*)(ws + OFF_DEN64);
  unsigned int* mxenc = (unsigned int*)(ws + OFF_MX);
  unsigned long long* adj = (unsigned long long*)(ws + OFF_ADJ);
  int*   cnts = (int*)(ws + OFF_CNT);
  int*   vcnt = cnts + 0;
  int*   nmp  = cnts + 2;

  // zero hist + virtual accumulators + mxenc + adjacency + counters + A_virtual
  hipMemsetAsync(ws + OFF_ZBEG, 0, (OFF_END - OFF_ZBEG) * sizeof(float), stream);
  hipMemsetAsync(out + OUT_AV, 0, (size_t)NN * NN * sizeof(float), stream);
  hipMemcpyAsync(out + OUT_POS, pos, (size_t)NN * 3 * sizeof(float),
                 hipMemcpyDeviceToDevice, stream);

  hmp_edge_prep<<<EE/256, 256, 0, stream>>>(ei, pos, ln, dirn, adj, cnth);
  hmp_csr_scan<<<1, 256, 0, stream>>>(cnth, rowp, curs);
  hmp_csr_scatter<<<EE/256, 256, 0, stream>>>(ei, curs, csr);

  { // R = relu(h_s@W1), G = h_s@Wg
    GemmJobs J = {};
    J.A = h_s;
    J.W[0] = W1; J.C[0] = R; J.Nc[0] = 128; J.act[0] = 1;
    J.W[1] = Wg; J.C[1] = G; J.Nc[1] = 64;  J.act[1] = 0;
    hmp_gemm_k128<<<dim3(64,2,2), 256, 0, stream>>>(J);
  }
  hmp_mul_p1<<<NN*96/256, 256, 0, stream>>>(h_v, G, P1);
  hmp_csr_msg_s<<<NN/4, 256, 0, stream>>>(csr, rowp, ei, ln, R, nullptr, S1s);
  hmp_csr_msg_v<<<NN/4, 256, 0, stream>>>(csr, rowp, ei, dirn, P1, G, nullptr, S1v);

  { // hl_s = S1s@W2 + h_s
    GemmJobs J = {};
    J.A = S1s; J.res = h_s;
    J.W[0] = W2; J.C[0] = hls; J.Nc[0] = 128; J.act[0] = 2;
    hmp_gemm_k128<<<dim3(64,2,1), 256, 0, stream>>>(J);
  }

  hmp_master<<<NN/4, 256, 0, stream>>>(hls, Wm1, bm1, Wm2, bm2, mval, mskf, out + OUT_M);
  hmp_compact<<<1, 256, 0, stream>>>(mskf, midx, nmp);

  { // Q, K, A1, A2, R2=relu(hl_s@W1), G2=hl_s@Wg
    GemmJobs J = {};
    J.A = hls;
    J.W[0] = Wq;          J.C[0] = Qb; J.Nc[0] = 128; J.act[0] = 0;
    J.W[1] = Wk;          J.C[1] = Kb; J.Nc[1] = 128; J.act[1] = 0;
    J.W[2] = Wa1;         J.C[2] = A1; J.Nc[2] = 128; J.act[2] = 0;
    J.W[3] = Wa1 + 16384; J.C[3] = A2; J.Nc[3] = 128; J.act[3] = 0;
    J.W[4] = W1;          J.C[4] = R2; J.Nc[4] = 128; J.act[4] = 1;
    J.W[5] = Wg;          J.C[5] = G2; J.Nc[5] = 64;  J.act[5] = 0;
    hmp_gemm_k128<<<dim3(64,2,6), 256, 0, stream>>>(J);
  }
  hmp_colsum_w3<<<1, 128, 0, stream>>>(Wa1, w3);
  hmp_hlv_p2<<<NN*96/256, 256, 0, stream>>>(h_v, S1v, G2, hlv, P2);

  hmp_attn3<<<(NN/8)*2, 256, 0, stream>>>(Qb, Kb, adj, midx, nmp, pt);
  hmp_topk_emit<<<NN/256, 256, 0, stream>>>(pt, midx, nmp, out + OUT_AV, vedg, vcnt);

  hmp_vedge_sc<<<512, 256, 0, stream>>>(vedg, vcnt, pos, A1, A2, w3, ba1, Wa2, ba2,
                                        lnv, dirv, sc, mxenc);
  hmp_vexp<<<128, 256, 0, stream>>>(vedg, vcnt, sc, mxenc, eexp, den64);

  // pass-2 real-edge messages (mask-gated CSR; writes S2s/S2v incl. zeros)
  hmp_csr_msg_s<<<NN/4, 256, 0, stream>>>(csr, rowp, ei, ln, R2, mskf, S2s);
  hmp_csr_msg_v<<<NN/4, 256, 0, stream>>>(csr, rowp, ei, dirn, P2, G2, mskf, S2v);
  // virtual-edge messages (i64 atomics)
  hmp_msgv_s<<<1024, 256, 0, stream>>>(vedg, vcnt, eexp, den64, lnv, R2, accs);
  hmp_msgv_v<<<1024, 256, 0, stream>>>(vedg, vcnt, eexp, den64, dirv, P2, G2, accv);
  // S2s += virtual part
  hmp_comb<<<NN*128/256, 256, 0, stream>>>(S2s, accs, NN*128);

  { // hf_s = (1-m)*hl_s + m*mask*(hl_s + S2s@W2)
    GemmJobs J = {};
    J.A = S2s; J.res = hls; J.mval = mval; J.maskf = mskf;
    J.W[0] = W2; J.C[0] = out + OUT_HFS; J.Nc[0] = 128; J.act[0] = 3;
    hmp_gemm_k128<<<dim3(64,2,1), 256, 0, stream>>>(J);
  }
  hmp_final_v<<<NN*96/256, 256, 0, stream>>>(hlv, S2v, accv, mval, mskf, out + OUT_HFV);
}